// Round 9
// baseline (392.662 us; speedup 1.0000x reference)
//
#include <hip/hip_runtime.h>

#define NN 50000
#define NE 800000
#define MPAD 50048    // 391 * 128
#define NBK 196       // buckets of 256 nodes
#define FB 98         // partition blocks
#define CH4 2048      // int4 per partition block (8192 edges)
#define EB4 200000    // NE/4
#define STAGE_CAP 6144

typedef __attribute__((ext_vector_type(8))) short short8;
typedef __attribute__((ext_vector_type(4))) float f32x4;

__device__ __forceinline__ ushort f2b(float f) {
    uint u = __builtin_bit_cast(uint, f);
    uint r = (u + 0x7fffu + ((u >> 16) & 1u)) >> 16;
    return (ushort)r;
}
__device__ __forceinline__ uint pk2(float a, float b) {
    return (uint)f2b(a) | ((uint)f2b(b) << 16);
}
__device__ __forceinline__ float blo(uint u) { return __builtin_bit_cast(float, u << 16); }
__device__ __forceinline__ float bhi(uint u) { return __builtin_bit_cast(float, u & 0xffff0000u); }

// ================= bucketed CSR build =================

__global__ __launch_bounds__(256) void k_f1(const int* __restrict__ dst, int* __restrict__ bhist) {
    __shared__ int h[NBK];
    for (int i = threadIdx.x; i < NBK; i += 256) h[i] = 0;
    __syncthreads();
    int i1 = min((int)(blockIdx.x + 1) * CH4, EB4);
    for (int i = blockIdx.x * CH4 + threadIdx.x; i < i1; i += 256) {
        int4 d = ((const int4*)dst)[i];
        atomicAdd(&h[d.x >> 8], 1);
        atomicAdd(&h[d.y >> 8], 1);
        atomicAdd(&h[d.z >> 8], 1);
        atomicAdd(&h[d.w >> 8], 1);
    }
    __syncthreads();
    for (int i = threadIdx.x; i < NBK; i += 256) bhist[blockIdx.x * NBK + i] = h[i];
}

__global__ __launch_bounds__(256) void k_fscan(const int* __restrict__ bhist,
                                               int* __restrict__ pairRel,
                                               int* __restrict__ bbase) {
    __shared__ int tot[256];
    int b = threadIdx.x;
    int run = 0;
    if (b < NBK) {
        for (int blk = 0; blk < FB; ++blk) {
            int v = bhist[blk * NBK + b];
            pairRel[blk * NBK + b] = run;
            run += v;
        }
    }
    tot[b] = (b < NBK) ? run : 0;
    __syncthreads();
    for (int off = 1; off < 256; off <<= 1) {
        int t = (b >= off) ? tot[b - off] : 0;
        __syncthreads();
        tot[b] += t;
        __syncthreads();
    }
    if (b < NBK) bbase[b] = tot[b] - run;
    if (b == NBK - 1) bbase[NBK] = tot[b];
}

__global__ __launch_bounds__(256) void k_f2(const int* __restrict__ src, const int* __restrict__ dst,
                                            const int* __restrict__ pairRel,
                                            const int* __restrict__ bbase, int2* __restrict__ pairs) {
    __shared__ int cur[NBK];
    for (int i = threadIdx.x; i < NBK; i += 256)
        cur[i] = bbase[i] + pairRel[blockIdx.x * NBK + i];
    __syncthreads();
    int i1 = min((int)(blockIdx.x + 1) * CH4, EB4);
    for (int i = blockIdx.x * CH4 + threadIdx.x; i < i1; i += 256) {
        int4 s = ((const int4*)src)[i];
        int4 d = ((const int4*)dst)[i];
        int p0 = atomicAdd(&cur[d.x >> 8], 1);
        int p1 = atomicAdd(&cur[d.y >> 8], 1);
        int p2 = atomicAdd(&cur[d.z >> 8], 1);
        int p3 = atomicAdd(&cur[d.w >> 8], 1);
        pairs[p0] = (int2){s.x, d.x};
        pairs[p1] = (int2){s.y, d.y};
        pairs[p2] = (int2){s.z, d.z};
        pairs[p3] = (int2){s.w, d.w};
    }
}

__global__ __launch_bounds__(256) void k_f3(const int2* __restrict__ pairs,
                                            const int* __restrict__ bbase,
                                            int* __restrict__ row_start,
                                            float* __restrict__ inv_deg,
                                            int* __restrict__ col) {
    __shared__ int ndeg[256];
    __shared__ int noff[256];
    __shared__ int stage[STAGE_CAP];
    int b = blockIdx.x;
    int base = bbase[b], end = bbase[b + 1];
    int nbase = b << 8;
    int t = threadIdx.x;
    ndeg[t] = 0;
    __syncthreads();
    for (int p = base + t; p < end; p += 256) atomicAdd(&ndeg[pairs[p].y - nbase], 1);
    __syncthreads();
    int d = ndeg[t];
    noff[t] = d;
    __syncthreads();
    for (int off = 1; off < 256; off <<= 1) {
        int v = (t >= off) ? noff[t - off] : 0;
        __syncthreads();
        noff[t] += v;
        __syncthreads();
    }
    int excl = noff[t] - d;
    int node = nbase + t;
    if (node < NN) {
        row_start[node] = base + excl;
        inv_deg[node] = 1.0f / (float)(d > 1 ? d : 1);
    }
    if (b == 0 && t == 0) row_start[NN] = NE;
    __syncthreads();
    noff[t] = excl;
    __syncthreads();
    int cnt = end - base;
    for (int p = base + t; p < end; p += 256) {
        int2 pr = pairs[p];
        int pos = atomicAdd(&noff[pr.y - nbase], 1);
        if (pos < STAGE_CAP) stage[pos] = pr.x;
        else col[base + pos] = pr.x;
    }
    __syncthreads();
    int lim = cnt < STAGE_CAP ? cnt : STAGE_CAP;
    for (int i = t; i < lim; i += 256) col[base + i] = stage[i];
}

// ================= conversions =================

__global__ void k_xcvt(const float* __restrict__ x, ushort* __restrict__ xb, int n2) {
    int i = blockIdx.x * blockDim.x + threadIdx.x;
    if (i < n2) {
        float2 v = *(const float2*)(x + (size_t)i * 2);
        *(uint*)(xb + (size_t)i * 2) = pk2(v.x, v.y);
    }
}

struct W2Args {
    const float* srcA[8];
    const float* srcB[8];
    ushort* dst[8];
};

__global__ void k_wcvt(W2Args a) {
    const int offT[8]   = {0, 16384, 49152, 57344, 65536, 81920, 114688, 122880};
    const int splitT[8] = {64, 128, 128, 0, 64, 128, 128, 0};
    const int logKKT[8] = {7, 8, 7, 7, 7, 8, 7, 7};
    const int ntT[8]    = {8, 8, 4, 4, 8, 8, 4, 4};
    int idx = blockIdx.x * blockDim.x + threadIdx.x;
    if (idx >= 131072) return;
    int L = 0;
#pragma unroll
    for (int i = 1; i < 8; ++i) if (idx >= offT[i]) L = i;
    int j = idx - offT[L];
    int lk = logKKT[L];
    int KK = 1 << lk;
    int n = j >> lk;
    int c = j & (KK - 1);
    int split = splitT[L];
    float v = (c < split) ? a.srcA[L][n * split + c]
                          : a.srcB[L][n * (KK - split) + (c - split)];
    int ks = c >> 5, kseg = (c >> 3) & 3, jj = c & 7;
    int nt = n >> 4, r15 = n & 15;
    int lane = (kseg << 4) | r15;
    int foff = ((ks * ntT[L] + nt) << 9) + (lane << 3) + jj;
    a.dst[L][foff] = f2b(v);
}

// ================= sliced mean aggregation =================
// Column-sliced gather: slice = blockIdx.x % NSLICE -> all blocks of a slice land
// on the same XCD(s) (round-robin dispatch), so each L2 only caches a 3.2MB
// 32-feature slice of the table. 4-lane group per node (4 x 16B = one 64B line).

__device__ __forceinline__ void acc8(float* a, uint4 u) {
    a[0] += blo(u.x); a[1] += bhi(u.x);
    a[2] += blo(u.y); a[3] += bhi(u.y);
    a[4] += blo(u.z); a[5] += bhi(u.z);
    a[6] += blo(u.w); a[7] += bhi(u.w);
}

template <int D, int NSLICE>
__global__ __launch_bounds__(256) void k_aggs(
    const ushort* __restrict__ h,
    const int* __restrict__ row_start, const int* __restrict__ col,
    const float* __restrict__ inv_deg, ushort* __restrict__ o) {
    int slice = blockIdx.x % NSLICE;
    int chunk = blockIdx.x / NSLICE;
    int node = chunk * 64 + (threadIdx.x >> 2);
    int li = threadIdx.x & 3;
    if (node >= NN) return;
    int s = row_start[node], e = row_start[node + 1];
    float sc = inv_deg[node];
    const ushort* hb = h + (size_t)slice * 32 + (size_t)li * 8;
    float a[8] = {0, 0, 0, 0, 0, 0, 0, 0};
    int p = s;
    for (; p + 7 < e; p += 8) {
        int c0 = col[p], c1 = col[p + 1], c2 = col[p + 2], c3 = col[p + 3];
        int c4 = col[p + 4], c5 = col[p + 5], c6 = col[p + 6], c7 = col[p + 7];
        uint4 u0 = *(const uint4*)(hb + (size_t)c0 * D);
        uint4 u1 = *(const uint4*)(hb + (size_t)c1 * D);
        uint4 u2 = *(const uint4*)(hb + (size_t)c2 * D);
        uint4 u3 = *(const uint4*)(hb + (size_t)c3 * D);
        uint4 u4 = *(const uint4*)(hb + (size_t)c4 * D);
        uint4 u5 = *(const uint4*)(hb + (size_t)c5 * D);
        uint4 u6 = *(const uint4*)(hb + (size_t)c6 * D);
        uint4 u7 = *(const uint4*)(hb + (size_t)c7 * D);
        acc8(a, u0); acc8(a, u1); acc8(a, u2); acc8(a, u3);
        acc8(a, u4); acc8(a, u5); acc8(a, u6); acc8(a, u7);
    }
    for (; p < e; ++p) acc8(a, *(const uint4*)(hb + (size_t)col[p] * D));
    uint4 r;
    r.x = pk2(a[0] * sc, a[1] * sc);
    r.y = pk2(a[2] * sc, a[3] * sc);
    r.z = pk2(a[4] * sc, a[5] * sc);
    r.w = pk2(a[6] * sc, a[7] * sc);
    *(uint4*)(o + (size_t)node * D + slice * 32 + li * 8) = r;
}

// ================= MFMA GEMM, LDS-resident fragment-ordered W =================

struct GArgs {
    const ushort *A1, *A2, *Wm, *Wv;
    const float *blm, *blv, *gm, *gv, *bbm, *bbv;
    void* out;
};

template <int KH, int NOUT, bool DO_LN, bool DUAL, int ASTR, int AOFFM, int OSTR, int OOFFM>
__global__ __launch_bounds__(256, 2) void k_gemm(GArgs a) {
    constexpr int NT = NOUT / 16;
    constexpr int NK = KH / 16;
    constexpr int TW = DUAL ? 2 : 1;
    constexpr int WCH = NOUT * KH * 4 / 16;
    __shared__ uint4 wlds[TW * WCH];

    int tid = threadIdx.x;
    int lane = tid & 63, wid = tid >> 6;
    int tow = DUAL ? 0 : blockIdx.y;
    int aoff = tow * AOFFM;

    {
        const uint4* w0 = (const uint4*)(tow ? a.Wv : a.Wm);
        for (int i = tid; i < WCH; i += 256) wlds[i] = w0[i];
        if (DUAL) {
            const uint4* w1 = (const uint4*)a.Wv;
            for (int i = tid; i < WCH; i += 256) wlds[WCH + i] = w1[i];
        }
    }

    int r15 = lane & 15, kseg = lane >> 4;
    int m0 = blockIdx.x * 128 + wid * 32;
    size_t ar0 = (size_t)(m0 + r15);
    size_t ar1 = (size_t)(m0 + 16 + r15);

    short8 af[2][NK];
#pragma unroll
    for (int ks = 0; ks < NK; ++ks) {
        int kc = ks * 32 + kseg * 8;
        af[0][ks] = (kc < KH) ? *(const short8*)(a.A1 + ar0 * ASTR + aoff + kc)
                              : *(const short8*)(a.A2 + ar0 * ASTR + aoff + (kc - KH));
        af[1][ks] = (kc < KH) ? *(const short8*)(a.A1 + ar1 * ASTR + aoff + kc)
                              : *(const short8*)(a.A2 + ar1 * ASTR + aoff + (kc - KH));
    }
    __syncthreads();

    f32x4 acc[TW][2][NT];
#pragma unroll
    for (int tt = 0; tt < TW; ++tt)
#pragma unroll
        for (int t = 0; t < 2; ++t)
#pragma unroll
            for (int nt = 0; nt < NT; ++nt) acc[tt][t][nt] = (f32x4){0.f, 0.f, 0.f, 0.f};

#pragma unroll
    for (int ks = 0; ks < NK; ++ks) {
#pragma unroll
        for (int nt = 0; nt < NT; ++nt) {
#pragma unroll
            for (int tt = 0; tt < TW; ++tt) {
                short8 w = *(const short8*)&wlds[tt * WCH + (ks * NT + nt) * 64 + lane];
                acc[tt][0][nt] = __builtin_amdgcn_mfma_f32_16x16x32_bf16(af[0][ks], w, acc[tt][0][nt], 0, 0, 0);
                acc[tt][1][nt] = __builtin_amdgcn_mfma_f32_16x16x32_bf16(af[1][ks], w, acc[tt][1][nt], 0, 0, 0);
            }
        }
    }

#pragma unroll
    for (int tt = 0; tt < TW; ++tt) {
        int tsel = DUAL ? tt : tow;
        int ooff = tsel * OOFFM;
        const float* bl = tsel ? a.blv : a.blm;
#pragma unroll
        for (int nt = 0; nt < NT; ++nt) {
            float bb = bl[nt * 16 + r15];
#pragma unroll
            for (int t = 0; t < 2; ++t)
#pragma unroll
                for (int r = 0; r < 4; ++r) acc[tt][t][nt][r] += bb;
        }
        if (DO_LN) {
            const float* g = tsel ? a.gv : a.gm;
            const float* b = tsel ? a.bbv : a.bbm;
#pragma unroll
            for (int t = 0; t < 2; ++t) {
                float s[4] = {0, 0, 0, 0}, q[4] = {0, 0, 0, 0};
#pragma unroll
                for (int nt = 0; nt < NT; ++nt)
#pragma unroll
                    for (int r = 0; r < 4; ++r) { float v = acc[tt][t][nt][r]; s[r] += v; q[r] += v * v; }
#pragma unroll
                for (int off = 1; off < 16; off <<= 1)
#pragma unroll
                    for (int r = 0; r < 4; ++r) { s[r] += __shfl_xor(s[r], off); q[r] += __shfl_xor(q[r], off); }
                float mean[4], rstd[4];
#pragma unroll
                for (int r = 0; r < 4; ++r) {
                    mean[r] = s[r] * (1.0f / NOUT);
                    float var = q[r] * (1.0f / NOUT) - mean[r] * mean[r];
                    rstd[r] = rsqrtf(var + 1e-5f);
                }
                ushort* out = (ushort*)a.out;
#pragma unroll
                for (int nt = 0; nt < NT; ++nt) {
                    int n = nt * 16 + r15;
                    float gg = g[n], bb = b[n];
#pragma unroll
                    for (int r = 0; r < 4; ++r) {
                        int row = m0 + t * 16 + kseg * 4 + r;
                        if (row < NN) {
                            float y = fmaxf((acc[tt][t][nt][r] - mean[r]) * rstd[r] * gg + bb, 0.0f);
                            out[(size_t)row * OSTR + ooff + n] = f2b(y);
                        }
                    }
                }
            }
        } else {
            float* out = (float*)a.out;
#pragma unroll
            for (int t = 0; t < 2; ++t)
#pragma unroll
                for (int nt = 0; nt < NT; ++nt) {
                    int n = nt * 16 + r15;
#pragma unroll
                    for (int r = 0; r < 4; ++r) {
                        int row = m0 + t * 16 + kseg * 4 + r;
                        if (row < NN) out[(size_t)row * OSTR + ooff + n] = acc[tt][t][nt][r];
                    }
                }
        }
    }
}

// ================= layer-2 split kernels (linearity) =================

struct G2Args {
    const ushort *A, *Wm, *Wv, *a2;
    const float *blm, *blv;
    void *outm, *outv;
};

template <bool FINAL>
__global__ __launch_bounds__(256, 2) void k_gemm2(G2Args a) {
    constexpr int NT = 4, NK = 4;
    constexpr int WCH = 1024;  // 16KB
    __shared__ uint4 wlds[WCH];

    int tid = threadIdx.x;
    int lane = tid & 63, wid = tid >> 6;
    int tow = blockIdx.y;
    {
        const uint4* w0 = (const uint4*)(tow ? a.Wv : a.Wm);
        for (int i = tid; i < WCH; i += 256) wlds[i] = w0[i];
    }
    int r15 = lane & 15, kseg = lane >> 4;
    int m0 = blockIdx.x * 128 + wid * 32;
    size_t ar0 = (size_t)(m0 + r15);
    size_t ar1 = (size_t)(m0 + 16 + r15);
    int aoff = tow * 128;

    short8 af[2][NK];
#pragma unroll
    for (int ks = 0; ks < NK; ++ks) {
        int kc = ks * 32 + kseg * 8;
        af[0][ks] = *(const short8*)(a.A + ar0 * 256 + aoff + kc);
        af[1][ks] = *(const short8*)(a.A + ar1 * 256 + aoff + kc);
    }
    __syncthreads();

    f32x4 acc[2][NT];
#pragma unroll
    for (int t = 0; t < 2; ++t)
#pragma unroll
        for (int nt = 0; nt < NT; ++nt) acc[t][nt] = (f32x4){0.f, 0.f, 0.f, 0.f};

#pragma unroll
    for (int ks = 0; ks < NK; ++ks) {
#pragma unroll
        for (int nt = 0; nt < NT; ++nt) {
            short8 w = *(const short8*)&wlds[(ks * NT + nt) * 64 + lane];
            acc[0][nt] = __builtin_amdgcn_mfma_f32_16x16x32_bf16(af[0][ks], w, acc[0][nt], 0, 0, 0);
            acc[1][nt] = __builtin_amdgcn_mfma_f32_16x16x32_bf16(af[1][ks], w, acc[1][nt], 0, 0, 0);
        }
    }

    if (FINAL) {
        const float* bl = tow ? a.blv : a.blm;
        float* out = (float*)(tow ? a.outv : a.outm);
#pragma unroll
        for (int t = 0; t < 2; ++t)
#pragma unroll
            for (int nt = 0; nt < NT; ++nt) {
                int n = nt * 16 + r15;
                float bb = bl[n];
#pragma unroll
                for (int r = 0; r < 4; ++r) {
                    int row = m0 + t * 16 + kseg * 4 + r;
                    if (row < NN) {
                        float av = blo((uint)a.a2[(size_t)row * 128 + tow * 64 + n]);
                        out[(size_t)row * 64 + n] = acc[t][nt][r] + bb + av;
                    }
                }
            }
    } else {
        ushort* out = (ushort*)a.outm;
#pragma unroll
        for (int t = 0; t < 2; ++t)
#pragma unroll
            for (int nt = 0; nt < NT; ++nt) {
                int n = nt * 16 + r15;
#pragma unroll
                for (int r = 0; r < 4; ++r) {
                    int row = m0 + t * 16 + kseg * 4 + r;
                    if (row < NN) out[(size_t)row * 128 + tow * 64 + n] = f2b(acc[t][nt][r]);
                }
            }
    }
}

// ================= launch =================

extern "C" void kernel_launch(void* const* d_in, const int* in_sizes, int n_in,
                              void* d_out, int out_size, void* d_ws, size_t ws_size,
                              hipStream_t stream) {
    const float* x = (const float*)d_in[0];
    const int* ei = (const int*)d_in[1];
    const int* esrc = ei;
    const int* edst = ei + NE;

    const float* mWl0 = (const float*)d_in[2];
    const float* mbl0 = (const float*)d_in[3];
    const float* mWr0 = (const float*)d_in[4];
    const float* mg0  = (const float*)d_in[5];
    const float* mb0  = (const float*)d_in[6];
    const float* mWl1 = (const float*)d_in[7];
    const float* mbl1 = (const float*)d_in[8];
    const float* mWr1 = (const float*)d_in[9];
    const float* mg1  = (const float*)d_in[10];
    const float* mb1  = (const float*)d_in[11];
    const float* mWl2 = (const float*)d_in[12];
    const float* mbl2 = (const float*)d_in[13];
    const float* mWr2 = (const float*)d_in[14];
    const float* vWl0 = (const float*)d_in[15];
    const float* vbl0 = (const float*)d_in[16];
    const float* vWr0 = (const float*)d_in[17];
    const float* vg0  = (const float*)d_in[18];
    const float* vb0  = (const float*)d_in[19];
    const float* vWl1 = (const float*)d_in[20];
    const float* vbl1 = (const float*)d_in[21];
    const float* vWr1 = (const float*)d_in[22];
    const float* vg1  = (const float*)d_in[23];
    const float* vb1  = (const float*)d_in[24];
    const float* vWl2 = (const float*)d_in[25];
    const float* vbl2 = (const float*)d_in[26];
    const float* vWr2 = (const float*)d_in[27];

    char* p = (char*)d_ws;
    auto alloc = [&](size_t bytes) {
        void* r = (void*)p;
        p += (bytes + 255) & ~(size_t)255;
        return r;
    };
    int* bhist     = (int*)alloc((size_t)FB * NBK * 4);
    int* pairRel   = (int*)alloc((size_t)FB * NBK * 4);
    int* bbase     = (int*)alloc((size_t)(NBK + 1) * 4);
    int* row_start = (int*)alloc((size_t)(NN + 1) * 4);
    float* inv_deg = (float*)alloc((size_t)NN * 4);
    int* col       = (int*)alloc((size_t)NE * 4);
    int2* pairs    = (int2*)alloc((size_t)NE * 8);     // reused as agg0 after F3
    ushort* agg0   = (ushort*)pairs;
    ushort* x_bf   = (ushort*)alloc((size_t)MPAD * 64 * 2);
    ushort* h1p    = (ushort*)alloc((size_t)MPAD * 256 * 2);
    ushort* h2p    = (ushort*)alloc((size_t)MPAD * 256 * 2);
    ushort* aggp   = (ushort*)alloc((size_t)MPAD * 256 * 2);
    ushort* p2     = aggp;
    ushort* a2     = aggp + (size_t)MPAD * 128;
    ushort* wc0    = (ushort*)alloc((size_t)128 * 128 * 2);
    ushort* wc1    = (ushort*)alloc((size_t)128 * 256 * 2);
    ushort* wc2    = (ushort*)alloc((size_t)64 * 128 * 2);
    ushort* wc3    = (ushort*)alloc((size_t)128 * 128 * 2);
    ushort* wc4    = (ushort*)alloc((size_t)128 * 256 * 2);
    ushort* wc5    = (ushort*)alloc((size_t)64 * 128 * 2);
    ushort* wc6    = (ushort*)alloc((size_t)64 * 128 * 2);
    ushort* wc7    = (ushort*)alloc((size_t)64 * 128 * 2);

    float* out_mu = (float*)d_out;
    float* out_lv = (float*)d_out + (size_t)NN * 64;

    // conversions (independent of CSR)
    k_xcvt<<<(NN * 64 / 2 + 255) / 256, 256, 0, stream>>>(x, x_bf, NN * 64 / 2);
    W2Args wa;
    wa.srcA[0] = mWl0; wa.srcB[0] = mWr0; wa.dst[0] = wc0;
    wa.srcA[1] = mWl1; wa.srcB[1] = mWr1; wa.dst[1] = wc1;
    wa.srcA[2] = mWl2; wa.srcB[2] = nullptr; wa.dst[2] = wc2;
    wa.srcA[3] = nullptr; wa.srcB[3] = mWr2; wa.dst[3] = wc6;
    wa.srcA[4] = vWl0; wa.srcB[4] = vWr0; wa.dst[4] = wc3;
    wa.srcA[5] = vWl1; wa.srcB[5] = vWr1; wa.dst[5] = wc4;
    wa.srcA[6] = vWl2; wa.srcB[6] = nullptr; wa.dst[6] = wc5;
    wa.srcA[7] = nullptr; wa.srcB[7] = vWr2; wa.dst[7] = wc7;
    k_wcvt<<<512, 256, 0, stream>>>(wa);

    // bucketed CSR build
    k_f1<<<FB, 256, 0, stream>>>(edst, bhist);
    k_fscan<<<1, 256, 0, stream>>>(bhist, pairRel, bbase);
    k_f2<<<FB, 256, 0, stream>>>(esrc, edst, pairRel, bbase, pairs);
    k_f3<<<196, 256, 0, stream>>>(pairs, bbase, row_start, inv_deg, col);

    const int CHK = (NN + 63) / 64;           // 782 node chunks
    const int gM = MPAD / 128;                // 391

    // layer 0: shared agg of x (2 slices); DUAL GEMM -> packed h1p
    k_aggs<64, 2><<<2 * CHK, 256, 0, stream>>>(x_bf, row_start, col, inv_deg, agg0);
    {
        GArgs ga = {agg0, x_bf, wc0, wc3, mbl0, vbl0, mg0, vg0, mb0, vb0, h1p};
        k_gemm<64, 128, true, true, 64, 0, 256, 128><<<dim3(gM, 1), 256, 0, stream>>>(ga);
    }
    // layer 1: sliced packed agg (8 slices), packed GEMM -> h2p
    k_aggs<256, 8><<<8 * CHK, 256, 0, stream>>>(h1p, row_start, col, inv_deg, aggp);
    {
        GArgs ga = {aggp, h1p, wc1, wc4, mbl1, vbl1, mg1, vg1, mb1, vb1, h2p};
        k_gemm<128, 128, true, false, 256, 128, 256, 128><<<dim3(gM, 2), 256, 0, stream>>>(ga);
    }
    // layer 2 via linearity: project (Wl) -> sliced agg (4 slices) -> final
    {
        G2Args g2 = {h2p, wc2, wc5, nullptr, nullptr, nullptr, p2, nullptr};
        k_gemm2<false><<<dim3(gM, 2), 256, 0, stream>>>(g2);
    }
    k_aggs<128, 4><<<4 * CHK, 256, 0, stream>>>(p2, row_start, col, inv_deg, a2);
    {
        G2Args g2 = {h2p, wc6, wc7, a2, mbl2, vbl2, out_mu, out_lv};
        k_gemm2<true><<<dim3(gM, 2), 256, 0, stream>>>(g2);
    }
}

// Round 10
// 375.532 us; speedup vs baseline: 1.0456x; 1.0456x over previous
//
#include <hip/hip_runtime.h>

#define NN 50000
#define NE 800000
#define MPAD 50048    // 391 * 128
#define NBK 196       // buckets of 256 nodes
#define FB 98         // partition blocks
#define CH4 2048      // int4 per partition block (8192 edges)
#define EB4 200000    // NE/4
#define STAGE_CAP 6144

typedef __attribute__((ext_vector_type(8))) short short8;
typedef __attribute__((ext_vector_type(4))) float f32x4;
typedef uint __attribute__((ext_vector_type(4))) uintx4;
typedef uint __attribute__((ext_vector_type(2))) uintx2;
typedef int __attribute__((ext_vector_type(2))) intx2;

__device__ __forceinline__ ushort f2b(float f) {
    uint u = __builtin_bit_cast(uint, f);
    uint r = (u + 0x7fffu + ((u >> 16) & 1u)) >> 16;
    return (ushort)r;
}
__device__ __forceinline__ uint pk2(float a, float b) {
    return (uint)f2b(a) | ((uint)f2b(b) << 16);
}
__device__ __forceinline__ float blo(uint u) { return __builtin_bit_cast(float, u << 16); }
__device__ __forceinline__ float bhi(uint u) { return __builtin_bit_cast(float, u & 0xffff0000u); }

__device__ __forceinline__ void acc8(float* a, uintx4 u) {
    a[0] += blo(u[0]); a[1] += bhi(u[0]);
    a[2] += blo(u[1]); a[3] += bhi(u[1]);
    a[4] += blo(u[2]); a[5] += bhi(u[2]);
    a[6] += blo(u[3]); a[7] += bhi(u[3]);
}
__device__ __forceinline__ void acc4(float* a, uintx2 u) {
    a[0] += blo(u[0]); a[1] += bhi(u[0]);
    a[2] += blo(u[1]); a[3] += bhi(u[1]);
}

// ================= weight conversion args =================

struct W2Args {
    const float* srcA[8];
    const float* srcB[8];
    ushort* dst[8];
};

// ================= merged prep: f1 hist | wcvt | xcvt =================

struct PrepArgs {
    const float* x; ushort* xb;
    W2Args w;
    const int* edst; int* bhist;
};

__global__ __launch_bounds__(256) void k_prep(PrepArgs a) {
    __shared__ int h[NBK];
    int b = blockIdx.x;
    int t = threadIdx.x;
    if (b < FB) {
        // f1: per-block bucket histogram
        for (int i = t; i < NBK; i += 256) h[i] = 0;
        __syncthreads();
        int i1 = min((b + 1) * CH4, EB4);
        for (int i = b * CH4 + t; i < i1; i += 256) {
            int4 d = ((const int4*)a.edst)[i];
            atomicAdd(&h[d.x >> 8], 1);
            atomicAdd(&h[d.y >> 8], 1);
            atomicAdd(&h[d.z >> 8], 1);
            atomicAdd(&h[d.w >> 8], 1);
        }
        __syncthreads();
        for (int i = t; i < NBK; i += 256) a.bhist[b * NBK + i] = h[i];
    } else if (b < FB + 512) {
        // wcvt: fragment-stream weight layout
        const int offT[8]   = {0, 16384, 49152, 57344, 65536, 81920, 114688, 122880};
        const int splitT[8] = {64, 128, 128, 0, 64, 128, 128, 0};
        const int logKKT[8] = {7, 8, 7, 7, 7, 8, 7, 7};
        const int ntT[8]    = {8, 8, 4, 4, 8, 8, 4, 4};
        int idx = (b - FB) * 256 + t;
        if (idx >= 131072) return;
        int L = 0;
#pragma unroll
        for (int i = 1; i < 8; ++i) if (idx >= offT[i]) L = i;
        int j = idx - offT[L];
        int lk = logKKT[L];
        int KK = 1 << lk;
        int n = j >> lk;
        int c = j & (KK - 1);
        int split = splitT[L];
        float v = (c < split) ? a.w.srcA[L][n * split + c]
                              : a.w.srcB[L][n * (KK - split) + (c - split)];
        int ks = c >> 5, kseg = (c >> 3) & 3, jj = c & 7;
        int nt = n >> 4, r15 = n & 15;
        int lane = (kseg << 4) | r15;
        int foff = ((ks * ntT[L] + nt) << 9) + (lane << 3) + jj;
        a.w.dst[L][foff] = f2b(v);
    } else {
        // xcvt
        int i = (b - FB - 512) * 256 + t;
        if (i < NN * 32) {
            float2 v = *(const float2*)(a.x + (size_t)i * 2);
            *(uint*)(a.xb + (size_t)i * 2) = pk2(v.x, v.y);
        }
    }
}

// ================= bucketed CSR build =================

__global__ __launch_bounds__(256) void k_fscan(const int* __restrict__ bhist,
                                               int* __restrict__ pairRel,
                                               int* __restrict__ bbase) {
    __shared__ int tot[256];
    int b = threadIdx.x;
    int run = 0;
    if (b < NBK) {
        for (int blk = 0; blk < FB; ++blk) {
            int v = bhist[blk * NBK + b];
            pairRel[blk * NBK + b] = run;
            run += v;
        }
    }
    tot[b] = (b < NBK) ? run : 0;
    __syncthreads();
    for (int off = 1; off < 256; off <<= 1) {
        int t = (b >= off) ? tot[b - off] : 0;
        __syncthreads();
        tot[b] += t;
        __syncthreads();
    }
    if (b < NBK) bbase[b] = tot[b] - run;
    if (b == NBK - 1) bbase[NBK] = tot[b];
}

__global__ __launch_bounds__(256) void k_f2(const int* __restrict__ src, const int* __restrict__ dst,
                                            const int* __restrict__ pairRel,
                                            const int* __restrict__ bbase, intx2* __restrict__ pairs) {
    __shared__ int cur[NBK];
    for (int i = threadIdx.x; i < NBK; i += 256)
        cur[i] = bbase[i] + pairRel[blockIdx.x * NBK + i];
    __syncthreads();
    int i1 = min((int)(blockIdx.x + 1) * CH4, EB4);
    for (int i = blockIdx.x * CH4 + threadIdx.x; i < i1; i += 256) {
        int4 s = ((const int4*)src)[i];
        int4 d = ((const int4*)dst)[i];
        int p0 = atomicAdd(&cur[d.x >> 8], 1);
        int p1 = atomicAdd(&cur[d.y >> 8], 1);
        int p2 = atomicAdd(&cur[d.z >> 8], 1);
        int p3 = atomicAdd(&cur[d.w >> 8], 1);
        __builtin_nontemporal_store((intx2){s.x, d.x}, &pairs[p0]);
        __builtin_nontemporal_store((intx2){s.y, d.y}, &pairs[p1]);
        __builtin_nontemporal_store((intx2){s.z, d.z}, &pairs[p2]);
        __builtin_nontemporal_store((intx2){s.w, d.w}, &pairs[p3]);
    }
}

__global__ __launch_bounds__(256) void k_f3(const intx2* __restrict__ pairs,
                                            const int* __restrict__ bbase,
                                            int* __restrict__ row_start,
                                            float* __restrict__ inv_deg,
                                            int* __restrict__ col) {
    __shared__ int ndeg[256];
    __shared__ int noff[256];
    __shared__ int stage[STAGE_CAP];
    int b = blockIdx.x;
    int base = bbase[b], end = bbase[b + 1];
    int nbase = b << 8;
    int t = threadIdx.x;
    ndeg[t] = 0;
    __syncthreads();
    for (int p = base + t; p < end; p += 256) {
        intx2 pr = pairs[p];
        atomicAdd(&ndeg[pr[1] - nbase], 1);
    }
    __syncthreads();
    int d = ndeg[t];
    noff[t] = d;
    __syncthreads();
    for (int off = 1; off < 256; off <<= 1) {
        int v = (t >= off) ? noff[t - off] : 0;
        __syncthreads();
        noff[t] += v;
        __syncthreads();
    }
    int excl = noff[t] - d;
    int node = nbase + t;
    if (node < NN) {
        row_start[node] = base + excl;
        inv_deg[node] = 1.0f / (float)(d > 1 ? d : 1);
    }
    if (b == 0 && t == 0) row_start[NN] = NE;
    __syncthreads();
    noff[t] = excl;
    __syncthreads();
    int cnt = end - base;
    for (int p = base + t; p < end; p += 256) {
        intx2 pr = pairs[p];
        int pos = atomicAdd(&noff[pr[1] - nbase], 1);
        if (pos < STAGE_CAP) stage[pos] = pr[0];
        else col[base + pos] = pr[0];
    }
    __syncthreads();
    int lim = cnt < STAGE_CAP ? cnt : STAGE_CAP;
    for (int i = t; i < lim; i += 256) col[base + i] = stage[i];
}

// ================= mean aggregation: 16-deep unroll, nt col/output =================
// D=64: 16 lanes/node x 8B; D=128: 16 lanes x 16B; D=256: 32 lanes x 16B.

template <int D>
__global__ __launch_bounds__(256) void k_agg(
    const ushort* __restrict__ h,
    const int* __restrict__ row_start, const int* __restrict__ col,
    const float* __restrict__ inv_deg, ushort* __restrict__ o) {
    constexpr int LPN = (D == 256) ? 32 : 16;
    int gid = blockIdx.x * 256 + threadIdx.x;
    int node = gid / LPN;
    int li = gid & (LPN - 1);
    if (node >= NN) return;
    int s = row_start[node], e = row_start[node + 1];
    float sc = inv_deg[node];
    if (D == 64) {
        const ushort* hb = h + li * 4;
        float a[4] = {0, 0, 0, 0};
        int p = s;
        for (; p + 15 < e; p += 16) {
            int cc[16];
#pragma unroll
            for (int j = 0; j < 16; ++j) cc[j] = __builtin_nontemporal_load(col + p + j);
#pragma unroll
            for (int j = 0; j < 16; ++j) acc4(a, *(const uintx2*)(hb + (size_t)cc[j] * 64));
        }
        for (; p + 3 < e; p += 4) {
            int cc[4];
#pragma unroll
            for (int j = 0; j < 4; ++j) cc[j] = __builtin_nontemporal_load(col + p + j);
#pragma unroll
            for (int j = 0; j < 4; ++j) acc4(a, *(const uintx2*)(hb + (size_t)cc[j] * 64));
        }
        for (; p < e; ++p) acc4(a, *(const uintx2*)(hb + (size_t)col[p] * 64));
        uintx2 r;
        r[0] = pk2(a[0] * sc, a[1] * sc);
        r[1] = pk2(a[2] * sc, a[3] * sc);
        __builtin_nontemporal_store(r, (uintx2*)(o + (size_t)node * 64 + li * 4));
    } else {
        const ushort* hb = h + li * 8;
        float a[8] = {0, 0, 0, 0, 0, 0, 0, 0};
        int p = s;
        for (; p + 15 < e; p += 16) {
            int cc[16];
#pragma unroll
            for (int j = 0; j < 16; ++j) cc[j] = __builtin_nontemporal_load(col + p + j);
#pragma unroll
            for (int j = 0; j < 16; ++j) acc8(a, *(const uintx4*)(hb + (size_t)cc[j] * D));
        }
        for (; p + 3 < e; p += 4) {
            int cc[4];
#pragma unroll
            for (int j = 0; j < 4; ++j) cc[j] = __builtin_nontemporal_load(col + p + j);
#pragma unroll
            for (int j = 0; j < 4; ++j) acc8(a, *(const uintx4*)(hb + (size_t)cc[j] * D));
        }
        for (; p < e; ++p) acc8(a, *(const uintx4*)(hb + (size_t)col[p] * D));
        uintx4 r;
        r[0] = pk2(a[0] * sc, a[1] * sc);
        r[1] = pk2(a[2] * sc, a[3] * sc);
        r[2] = pk2(a[4] * sc, a[5] * sc);
        r[3] = pk2(a[6] * sc, a[7] * sc);
        __builtin_nontemporal_store(r, (uintx4*)(o + (size_t)node * D + li * 8));
    }
}

// ================= MFMA GEMM, LDS-resident fragment-ordered W =================

struct GArgs {
    const ushort *A1, *A2, *Wm, *Wv;
    const float *blm, *blv, *gm, *gv, *bbm, *bbv;
    void* out;
};

template <int KH, int NOUT, bool DO_LN, bool DUAL, int ASTR, int AOFFM, int OSTR, int OOFFM>
__global__ __launch_bounds__(256, 2) void k_gemm(GArgs a) {
    constexpr int NT = NOUT / 16;
    constexpr int NK = KH / 16;
    constexpr int TW = DUAL ? 2 : 1;
    constexpr int WCH = NOUT * KH * 4 / 16;
    __shared__ uint4 wlds[TW * WCH];

    int tid = threadIdx.x;
    int lane = tid & 63, wid = tid >> 6;
    int tow = DUAL ? 0 : blockIdx.y;
    int aoff = tow * AOFFM;

    {
        const uint4* w0 = (const uint4*)(tow ? a.Wv : a.Wm);
        for (int i = tid; i < WCH; i += 256) wlds[i] = w0[i];
        if (DUAL) {
            const uint4* w1 = (const uint4*)a.Wv;
            for (int i = tid; i < WCH; i += 256) wlds[WCH + i] = w1[i];
        }
    }

    int r15 = lane & 15, kseg = lane >> 4;
    int m0 = blockIdx.x * 128 + wid * 32;
    size_t ar0 = (size_t)(m0 + r15);
    size_t ar1 = (size_t)(m0 + 16 + r15);

    short8 af[2][NK];
#pragma unroll
    for (int ks = 0; ks < NK; ++ks) {
        int kc = ks * 32 + kseg * 8;
        af[0][ks] = (kc < KH) ? *(const short8*)(a.A1 + ar0 * ASTR + aoff + kc)
                              : *(const short8*)(a.A2 + ar0 * ASTR + aoff + (kc - KH));
        af[1][ks] = (kc < KH) ? *(const short8*)(a.A1 + ar1 * ASTR + aoff + kc)
                              : *(const short8*)(a.A2 + ar1 * ASTR + aoff + (kc - KH));
    }
    __syncthreads();

    f32x4 acc[TW][2][NT];
#pragma unroll
    for (int tt = 0; tt < TW; ++tt)
#pragma unroll
        for (int t = 0; t < 2; ++t)
#pragma unroll
            for (int nt = 0; nt < NT; ++nt) acc[tt][t][nt] = (f32x4){0.f, 0.f, 0.f, 0.f};

#pragma unroll
    for (int ks = 0; ks < NK; ++ks) {
#pragma unroll
        for (int nt = 0; nt < NT; ++nt) {
#pragma unroll
            for (int tt = 0; tt < TW; ++tt) {
                short8 w = *(const short8*)&wlds[tt * WCH + (ks * NT + nt) * 64 + lane];
                acc[tt][0][nt] = __builtin_amdgcn_mfma_f32_16x16x32_bf16(af[0][ks], w, acc[tt][0][nt], 0, 0, 0);
                acc[tt][1][nt] = __builtin_amdgcn_mfma_f32_16x16x32_bf16(af[1][ks], w, acc[tt][1][nt], 0, 0, 0);
            }
        }
    }

#pragma unroll
    for (int tt = 0; tt < TW; ++tt) {
        int tsel = DUAL ? tt : tow;
        int ooff = tsel * OOFFM;
        const float* bl = tsel ? a.blv : a.blm;
#pragma unroll
        for (int nt = 0; nt < NT; ++nt) {
            float bb = bl[nt * 16 + r15];
#pragma unroll
            for (int t = 0; t < 2; ++t)
#pragma unroll
                for (int r = 0; r < 4; ++r) acc[tt][t][nt][r] += bb;
        }
        if (DO_LN) {
            const float* g = tsel ? a.gv : a.gm;
            const float* b = tsel ? a.bbv : a.bbm;
#pragma unroll
            for (int t = 0; t < 2; ++t) {
                float s[4] = {0, 0, 0, 0}, q[4] = {0, 0, 0, 0};
#pragma unroll
                for (int nt = 0; nt < NT; ++nt)
#pragma unroll
                    for (int r = 0; r < 4; ++r) { float v = acc[tt][t][nt][r]; s[r] += v; q[r] += v * v; }
#pragma unroll
                for (int off = 1; off < 16; off <<= 1)
#pragma unroll
                    for (int r = 0; r < 4; ++r) { s[r] += __shfl_xor(s[r], off); q[r] += __shfl_xor(q[r], off); }
                float mean[4], rstd[4];
#pragma unroll
                for (int r = 0; r < 4; ++r) {
                    mean[r] = s[r] * (1.0f / NOUT);
                    float var = q[r] * (1.0f / NOUT) - mean[r] * mean[r];
                    rstd[r] = rsqrtf(var + 1e-5f);
                }
                ushort* out = (ushort*)a.out;
#pragma unroll
                for (int nt = 0; nt < NT; ++nt) {
                    int n = nt * 16 + r15;
                    float gg = g[n], bb = b[n];
#pragma unroll
                    for (int r = 0; r < 4; ++r) {
                        int row = m0 + t * 16 + kseg * 4 + r;
                        if (row < NN) {
                            float y = fmaxf((acc[tt][t][nt][r] - mean[r]) * rstd[r] * gg + bb, 0.0f);
                            out[(size_t)row * OSTR + ooff + n] = f2b(y);
                        }
                    }
                }
            }
        } else {
            float* out = (float*)a.out;
#pragma unroll
            for (int t = 0; t < 2; ++t)
#pragma unroll
                for (int nt = 0; nt < NT; ++nt) {
                    int n = nt * 16 + r15;
#pragma unroll
                    for (int r = 0; r < 4; ++r) {
                        int row = m0 + t * 16 + kseg * 4 + r;
                        if (row < NN) out[(size_t)row * OSTR + ooff + n] = acc[tt][t][nt][r];
                    }
                }
        }
    }
}

// ================= layer-2 split kernels (linearity) =================

struct G2Args {
    const ushort *A, *Wm, *Wv, *a2;
    const float *blm, *blv;
    void *outm, *outv;
};

template <bool FINAL>
__global__ __launch_bounds__(256, 2) void k_gemm2(G2Args a) {
    constexpr int NT = 4, NK = 4;
    constexpr int WCH = 1024;  // 16KB
    __shared__ uint4 wlds[WCH];

    int tid = threadIdx.x;
    int lane = tid & 63, wid = tid >> 6;
    int tow = blockIdx.y;
    {
        const uint4* w0 = (const uint4*)(tow ? a.Wv : a.Wm);
        for (int i = tid; i < WCH; i += 256) wlds[i] = w0[i];
    }
    int r15 = lane & 15, kseg = lane >> 4;
    int m0 = blockIdx.x * 128 + wid * 32;
    size_t ar0 = (size_t)(m0 + r15);
    size_t ar1 = (size_t)(m0 + 16 + r15);
    int aoff = tow * 128;

    short8 af[2][NK];
#pragma unroll
    for (int ks = 0; ks < NK; ++ks) {
        int kc = ks * 32 + kseg * 8;
        af[0][ks] = *(const short8*)(a.A + ar0 * 256 + aoff + kc);
        af[1][ks] = *(const short8*)(a.A + ar1 * 256 + aoff + kc);
    }
    __syncthreads();

    f32x4 acc[2][NT];
#pragma unroll
    for (int t = 0; t < 2; ++t)
#pragma unroll
        for (int nt = 0; nt < NT; ++nt) acc[t][nt] = (f32x4){0.f, 0.f, 0.f, 0.f};

#pragma unroll
    for (int ks = 0; ks < NK; ++ks) {
#pragma unroll
        for (int nt = 0; nt < NT; ++nt) {
            short8 w = *(const short8*)&wlds[(ks * NT + nt) * 64 + lane];
            acc[0][nt] = __builtin_amdgcn_mfma_f32_16x16x32_bf16(af[0][ks], w, acc[0][nt], 0, 0, 0);
            acc[1][nt] = __builtin_amdgcn_mfma_f32_16x16x32_bf16(af[1][ks], w, acc[1][nt], 0, 0, 0);
        }
    }

    if (FINAL) {
        const float* bl = tow ? a.blv : a.blm;
        float* out = (float*)(tow ? a.outv : a.outm);
#pragma unroll
        for (int t = 0; t < 2; ++t)
#pragma unroll
            for (int nt = 0; nt < NT; ++nt) {
                int n = nt * 16 + r15;
                float bb = bl[n];
#pragma unroll
                for (int r = 0; r < 4; ++r) {
                    int row = m0 + t * 16 + kseg * 4 + r;
                    if (row < NN) {
                        float av = blo((uint)a.a2[(size_t)row * 128 + tow * 64 + n]);
                        out[(size_t)row * 64 + n] = acc[t][nt][r] + bb + av;
                    }
                }
            }
    } else {
        ushort* out = (ushort*)a.outm;
#pragma unroll
        for (int t = 0; t < 2; ++t)
#pragma unroll
            for (int nt = 0; nt < NT; ++nt) {
                int n = nt * 16 + r15;
#pragma unroll
                for (int r = 0; r < 4; ++r) {
                    int row = m0 + t * 16 + kseg * 4 + r;
                    if (row < NN) out[(size_t)row * 128 + tow * 64 + n] = f2b(acc[t][nt][r]);
                }
            }
    }
}

// ================= launch =================

extern "C" void kernel_launch(void* const* d_in, const int* in_sizes, int n_in,
                              void* d_out, int out_size, void* d_ws, size_t ws_size,
                              hipStream_t stream) {
    const float* x = (const float*)d_in[0];
    const int* ei = (const int*)d_in[1];
    const int* esrc = ei;
    const int* edst = ei + NE;

    const float* mWl0 = (const float*)d_in[2];
    const float* mbl0 = (const float*)d_in[3];
    const float* mWr0 = (const float*)d_in[4];
    const float* mg0  = (const float*)d_in[5];
    const float* mb0  = (const float*)d_in[6];
    const float* mWl1 = (const float*)d_in[7];
    const float* mbl1 = (const float*)d_in[8];
    const float* mWr1 = (const float*)d_in[9];
    const float* mg1  = (const float*)d_in[10];
    const float* mb1  = (const float*)d_in[11];
    const float* mWl2 = (const float*)d_in[12];
    const float* mbl2 = (const float*)d_in[13];
    const float* mWr2 = (const float*)d_in[14];
    const float* vWl0 = (const float*)d_in[15];
    const float* vbl0 = (const float*)d_in[16];
    const float* vWr0 = (const float*)d_in[17];
    const float* vg0  = (const float*)d_in[18];
    const float* vb0  = (const float*)d_in[19];
    const float* vWl1 = (const float*)d_in[20];
    const float* vbl1 = (const float*)d_in[21];
    const float* vWr1 = (const float*)d_in[22];
    const float* vg1  = (const float*)d_in[23];
    const float* vb1  = (const float*)d_in[24];
    const float* vWl2 = (const float*)d_in[25];
    const float* vbl2 = (const float*)d_in[26];
    const float* vWr2 = (const float*)d_in[27];

    char* p = (char*)d_ws;
    auto alloc = [&](size_t bytes) {
        void* r = (void*)p;
        p += (bytes + 255) & ~(size_t)255;
        return r;
    };
    int* bhist     = (int*)alloc((size_t)FB * NBK * 4);
    int* pairRel   = (int*)alloc((size_t)FB * NBK * 4);
    int* bbase     = (int*)alloc((size_t)(NBK + 1) * 4);
    int* row_start = (int*)alloc((size_t)(NN + 1) * 4);
    float* inv_deg = (float*)alloc((size_t)NN * 4);
    int* col       = (int*)alloc((size_t)NE * 4);
    intx2* pairs   = (intx2*)alloc((size_t)NE * 8);   // reused as agg0 after F3
    ushort* agg0   = (ushort*)pairs;
    ushort* x_bf   = (ushort*)alloc((size_t)MPAD * 64 * 2);
    ushort* h1p    = (ushort*)alloc((size_t)MPAD * 256 * 2);
    ushort* h2p    = (ushort*)alloc((size_t)MPAD * 256 * 2);
    ushort* aggp   = (ushort*)alloc((size_t)MPAD * 256 * 2);
    ushort* p2     = aggp;
    ushort* a2     = aggp + (size_t)MPAD * 128;
    ushort* wc0    = (ushort*)alloc((size_t)128 * 128 * 2);
    ushort* wc1    = (ushort*)alloc((size_t)128 * 256 * 2);
    ushort* wc2    = (ushort*)alloc((size_t)64 * 128 * 2);
    ushort* wc3    = (ushort*)alloc((size_t)128 * 128 * 2);
    ushort* wc4    = (ushort*)alloc((size_t)128 * 256 * 2);
    ushort* wc5    = (ushort*)alloc((size_t)64 * 128 * 2);
    ushort* wc6    = (ushort*)alloc((size_t)64 * 128 * 2);
    ushort* wc7    = (ushort*)alloc((size_t)64 * 128 * 2);

    float* out_mu = (float*)d_out;
    float* out_lv = (float*)d_out + (size_t)NN * 64;

    // merged prep: f1 hist + weight cvt + x cvt (one dispatch)
    PrepArgs pa;
    pa.x = x; pa.xb = x_bf; pa.edst = edst; pa.bhist = bhist;
    pa.w.srcA[0] = mWl0; pa.w.srcB[0] = mWr0; pa.w.dst[0] = wc0;
    pa.w.srcA[1] = mWl1; pa.w.srcB[1] = mWr1; pa.w.dst[1] = wc1;
    pa.w.srcA[2] = mWl2; pa.w.srcB[2] = nullptr; pa.w.dst[2] = wc2;
    pa.w.srcA[3] = nullptr; pa.w.srcB[3] = mWr2; pa.w.dst[3] = wc6;
    pa.w.srcA[4] = vWl0; pa.w.srcB[4] = vWr0; pa.w.dst[4] = wc3;
    pa.w.srcA[5] = vWl1; pa.w.srcB[5] = vWr1; pa.w.dst[5] = wc4;
    pa.w.srcA[6] = vWl2; pa.w.srcB[6] = nullptr; pa.w.dst[6] = wc5;
    pa.w.srcA[7] = nullptr; pa.w.srcB[7] = vWr2; pa.w.dst[7] = wc7;
    k_prep<<<FB + 512 + (NN * 32 + 255) / 256, 256, 0, stream>>>(pa);

    // bucketed CSR build
    k_fscan<<<1, 256, 0, stream>>>(bhist, pairRel, bbase);
    k_f2<<<FB, 256, 0, stream>>>(esrc, edst, pairRel, bbase, pairs);
    k_f3<<<NBK, 256, 0, stream>>>(pairs, bbase, row_start, inv_deg, col);

    const int gM = MPAD / 128;  // 391

    // layer 0: shared agg of x; DUAL GEMM -> packed h1p
    k_agg<64><<<(NN * 16 + 255) / 256, 256, 0, stream>>>(x_bf, row_start, col, inv_deg, agg0);
    {
        GArgs ga = {agg0, x_bf, wc0, wc3, mbl0, vbl0, mg0, vg0, mb0, vb0, h1p};
        k_gemm<64, 128, true, true, 64, 0, 256, 128><<<dim3(gM, 1), 256, 0, stream>>>(ga);
    }
    // layer 1: single packed agg pass, packed GEMM -> h2p
    k_agg<256><<<(NN * 32 + 255) / 256, 256, 0, stream>>>(h1p, row_start, col, inv_deg, aggp);
    {
        GArgs ga = {aggp, h1p, wc1, wc4, mbl1, vbl1, mg1, vg1, mb1, vb1, h2p};
        k_gemm<128, 128, true, false, 256, 128, 256, 128><<<dim3(gM, 2), 256, 0, stream>>>(ga);
    }
    // layer 2 via linearity: project (Wl) -> single agg -> final (Wr + agg + bias)
    {
        G2Args g2 = {h2p, wc2, wc5, nullptr, nullptr, nullptr, p2, nullptr};
        k_gemm2<false><<<dim3(gM, 2), 256, 0, stream>>>(g2);
    }
    k_agg<128><<<(NN * 16 + 255) / 256, 256, 0, stream>>>(p2, row_start, col, inv_deg, a2);
    {
        G2Args g2 = {h2p, wc6, wc7, a2, mbl2, vbl2, out_mu, out_lv};
        k_gemm2<true><<<dim3(gM, 2), 256, 0, stream>>>(g2);
    }
}

// Round 12
// 352.579 us; speedup vs baseline: 1.1137x; 1.0651x over previous
//
#include <hip/hip_runtime.h>

#define NN 50000
#define NE 800000
#define MPAD 50048    // 391 * 128
#define NBK 196       // buckets of 256 nodes
#define FB 98         // partition blocks
#define CH4 2048      // int4 per partition block (8192 edges)
#define EB4 200000    // NE/4
#define STAGE_CAP 6144

typedef __attribute__((ext_vector_type(8))) short short8;
typedef __attribute__((ext_vector_type(4))) float f32x4;
typedef uint __attribute__((ext_vector_type(4))) uintx4;
typedef uint __attribute__((ext_vector_type(2))) uintx2;

__device__ __forceinline__ ushort f2b(float f) {
    uint u = __builtin_bit_cast(uint, f);
    uint r = (u + 0x7fffu + ((u >> 16) & 1u)) >> 16;
    return (ushort)r;
}
__device__ __forceinline__ uint pk2(float a, float b) {
    return (uint)f2b(a) | ((uint)f2b(b) << 16);
}
__device__ __forceinline__ float blo(uint u) { return __builtin_bit_cast(float, u << 16); }
__device__ __forceinline__ float bhi(uint u) { return __builtin_bit_cast(float, u & 0xffff0000u); }

// ---- custom fp8 (e4m3-compatible, mul-trick codec) ----
// value = bitcast<f32>(payload7 << 20) * 2^120  (handles subnormals implicitly)
__device__ __forceinline__ uint enc8u(float y) {   // y >= 0, y < 448
    uint b = __builtin_bit_cast(uint, y * 0x1p-120f) + (1u << 19);  // RN at bit 20
    return (b >> 20) & 0x7fu;
}
__device__ __forceinline__ uint enc8s(float y) {
    uint sb = __builtin_bit_cast(uint, y) & 0x80000000u;
    uint b = __builtin_bit_cast(uint, fabsf(y) * 0x1p-120f) + (1u << 19);
    return ((b >> 20) & 0x7fu) | (sb >> 24);
}

__device__ __forceinline__ void acc8(float* a, uintx4 u) {
    a[0] += blo(u[0]); a[1] += bhi(u[0]);
    a[2] += blo(u[1]); a[3] += bhi(u[1]);
    a[4] += blo(u[2]); a[5] += bhi(u[2]);
    a[6] += blo(u[3]); a[7] += bhi(u[3]);
}
__device__ __forceinline__ void acc4(float* a, uintx2 u) {
    a[0] += blo(u[0]); a[1] += bhi(u[0]);
    a[2] += blo(u[1]); a[3] += bhi(u[1]);
}
template <bool SIGNED>
__device__ __forceinline__ void accf8(float* a, uintx2 u, float c120) {
#pragma unroll
    for (int w = 0; w < 2; ++w) {
        uint v = u[w];
#pragma unroll
        for (int j = 0; j < 4; ++j) {
            uint b = (v >> (8 * j)) & 0xffu;
            uint f = SIGNED ? (((b & 0x80u) << 24) | ((b & 0x7fu) << 20)) : (b << 20);
            a[w * 4 + j] += __builtin_bit_cast(float, f) * c120;
        }
    }
}

// ================= weight conversion args =================

struct W2Args {
    const float* srcA[8];
    const float* srcB[8];
    ushort* dst[8];
};

// ================= merged prep: f1 hist | wcvt | xcvt =================

struct PrepArgs {
    const float* x; ushort* xb;
    W2Args w;
    const int* edst; int* bhist;
};

__global__ __launch_bounds__(256) void k_prep(PrepArgs a) {
    __shared__ int h[NBK];
    int b = blockIdx.x;
    int t = threadIdx.x;
    if (b < FB) {
        for (int i = t; i < NBK; i += 256) h[i] = 0;
        __syncthreads();
        int i1 = min((b + 1) * CH4, EB4);
        for (int i = b * CH4 + t; i < i1; i += 256) {
            int4 d = ((const int4*)a.edst)[i];
            atomicAdd(&h[d.x >> 8], 1);
            atomicAdd(&h[d.y >> 8], 1);
            atomicAdd(&h[d.z >> 8], 1);
            atomicAdd(&h[d.w >> 8], 1);
        }
        __syncthreads();
        for (int i = t; i < NBK; i += 256) a.bhist[b * NBK + i] = h[i];
    } else if (b < FB + 512) {
        const int offT[8]   = {0, 16384, 49152, 57344, 65536, 81920, 114688, 122880};
        const int splitT[8] = {64, 128, 128, 0, 64, 128, 128, 0};
        const int logKKT[8] = {7, 8, 7, 7, 7, 8, 7, 7};
        const int ntT[8]    = {8, 8, 4, 4, 8, 8, 4, 4};
        int idx = (b - FB) * 256 + t;
        if (idx >= 131072) return;
        int L = 0;
#pragma unroll
        for (int i = 1; i < 8; ++i) if (idx >= offT[i]) L = i;
        int j = idx - offT[L];
        int lk = logKKT[L];
        int KK = 1 << lk;
        int n = j >> lk;
        int c = j & (KK - 1);
        int split = splitT[L];
        float v = (c < split) ? a.w.srcA[L][n * split + c]
                              : a.w.srcB[L][n * (KK - split) + (c - split)];
        int ks = c >> 5, kseg = (c >> 3) & 3, jj = c & 7;
        int nt = n >> 4, r15 = n & 15;
        int lane = (kseg << 4) | r15;
        int foff = ((ks * ntT[L] + nt) << 9) + (lane << 3) + jj;
        a.w.dst[L][foff] = f2b(v);
    } else {
        int i = (b - FB - 512) * 256 + t;
        if (i < NN * 32) {
            float2 v = *(const float2*)(a.x + (size_t)i * 2);
            *(uint*)(a.xb + (size_t)i * 2) = pk2(v.x, v.y);
        }
    }
}

// ================= bucketed CSR build =================

__global__ __launch_bounds__(256) void k_fscan(const int* __restrict__ bhist,
                                               int* __restrict__ pairRel,
                                               int* __restrict__ bbase) {
    __shared__ int tot[256];
    int b = threadIdx.x;
    int run = 0;
    if (b < NBK) {
        for (int blk = 0; blk < FB; ++blk) {
            int v = bhist[blk * NBK + b];
            pairRel[blk * NBK + b] = run;
            run += v;
        }
    }
    tot[b] = (b < NBK) ? run : 0;
    __syncthreads();
    for (int off = 1; off < 256; off <<= 1) {
        int t = (b >= off) ? tot[b - off] : 0;
        __syncthreads();
        tot[b] += t;
        __syncthreads();
    }
    if (b < NBK) bbase[b] = tot[b] - run;
    if (b == NBK - 1) bbase[NBK] = tot[b];
}

__global__ __launch_bounds__(256) void k_f2(const int* __restrict__ src, const int* __restrict__ dst,
                                            const int* __restrict__ pairRel,
                                            const int* __restrict__ bbase, int2* __restrict__ pairs) {
    __shared__ int cur[NBK];
    for (int i = threadIdx.x; i < NBK; i += 256)
        cur[i] = bbase[i] + pairRel[blockIdx.x * NBK + i];
    __syncthreads();
    int i1 = min((int)(blockIdx.x + 1) * CH4, EB4);
    for (int i = blockIdx.x * CH4 + threadIdx.x; i < i1; i += 256) {
        int4 s = ((const int4*)src)[i];
        int4 d = ((const int4*)dst)[i];
        int p0 = atomicAdd(&cur[d.x >> 8], 1);
        int p1 = atomicAdd(&cur[d.y >> 8], 1);
        int p2 = atomicAdd(&cur[d.z >> 8], 1);
        int p3 = atomicAdd(&cur[d.w >> 8], 1);
        pairs[p0] = (int2){s.x, d.x};
        pairs[p1] = (int2){s.y, d.y};
        pairs[p2] = (int2){s.z, d.z};
        pairs[p3] = (int2){s.w, d.w};
    }
}

__global__ __launch_bounds__(256) void k_f3(const int2* __restrict__ pairs,
                                            const int* __restrict__ bbase,
                                            int* __restrict__ row_start,
                                            float* __restrict__ inv_deg,
                                            int* __restrict__ col) {
    __shared__ int ndeg[256];
    __shared__ int noff[256];
    __shared__ int stage[STAGE_CAP];
    int b = blockIdx.x;
    int base = bbase[b], end = bbase[b + 1];
    int nbase = b << 8;
    int t = threadIdx.x;
    ndeg[t] = 0;
    __syncthreads();
    for (int p = base + t; p < end; p += 256) atomicAdd(&ndeg[pairs[p].y - nbase], 1);
    __syncthreads();
    int d = ndeg[t];
    noff[t] = d;
    __syncthreads();
    for (int off = 1; off < 256; off <<= 1) {
        int v = (t >= off) ? noff[t - off] : 0;
        __syncthreads();
        noff[t] += v;
        __syncthreads();
    }
    int excl = noff[t] - d;
    int node = nbase + t;
    if (node < NN) {
        row_start[node] = base + excl;
        inv_deg[node] = 1.0f / (float)(d > 1 ? d : 1);
    }
    if (b == 0 && t == 0) row_start[NN] = NE;
    __syncthreads();
    noff[t] = excl;
    __syncthreads();
    int cnt = end - base;
    for (int p = base + t; p < end; p += 256) {
        int2 pr = pairs[p];
        int pos = atomicAdd(&noff[pr.y - nbase], 1);
        if (pos < STAGE_CAP) stage[pos] = pr.x;
        else col[base + pos] = pr.x;
    }
    __syncthreads();
    int lim = cnt < STAGE_CAP ? cnt : STAGE_CAP;
    for (int i = t; i < lim; i += 256) col[base + i] = stage[i];
}

// ================= bf16 mean aggregation (layer 0, x table) =================

__global__ __launch_bounds__(256) void k_agg64(
    const ushort* __restrict__ h,
    const int* __restrict__ row_start, const int* __restrict__ col,
    const float* __restrict__ inv_deg, ushort* __restrict__ o) {
    int gid = blockIdx.x * 256 + threadIdx.x;
    int node = gid >> 4;
    int li = gid & 15;
    if (node >= NN) return;
    int s = row_start[node], e = row_start[node + 1];
    float sc = inv_deg[node];
    const ushort* hb = h + li * 4;
    float a[4] = {0, 0, 0, 0};
    int p = s;
    for (; p + 7 < e; p += 8) {
        int cc[8];
#pragma unroll
        for (int j = 0; j < 8; ++j) cc[j] = __builtin_nontemporal_load(col + p + j);
#pragma unroll
        for (int j = 0; j < 8; ++j) acc4(a, *(const uintx2*)(hb + (size_t)cc[j] * 64));
    }
    for (; p < e; ++p) acc4(a, *(const uintx2*)(hb + (size_t)col[p] * 64));
    uintx2 r;
    r[0] = pk2(a[0] * sc, a[1] * sc);
    r[1] = pk2(a[2] * sc, a[3] * sc);
    *(uintx2*)(o + (size_t)node * 64 + li * 4) = r;
}

// ================= fp8 mean aggregation (layers 1/2 tables) =================
// D bytes per row; 8 bytes (8 elems) per lane; bf16 output.

template <int D, bool SIGNED>
__global__ __launch_bounds__(256) void k_agg8(
    const uchar* __restrict__ h,
    const int* __restrict__ row_start, const int* __restrict__ col,
    const float* __restrict__ inv_deg, ushort* __restrict__ o) {
    constexpr int LPN = D / 8;
    int gid = blockIdx.x * 256 + threadIdx.x;
    int node = gid / LPN;
    int li = gid & (LPN - 1);
    if (node >= NN) return;
    int s = row_start[node], e = row_start[node + 1];
    float sc = inv_deg[node];
    const uchar* hb = h + li * 8;
    const float c120 = 0x1p120f;
    float a[8] = {0, 0, 0, 0, 0, 0, 0, 0};
    int p = s;
    for (; p + 7 < e; p += 8) {
        int cc[8];
#pragma unroll
        for (int j = 0; j < 8; ++j) cc[j] = __builtin_nontemporal_load(col + p + j);
#pragma unroll
        for (int j = 0; j < 8; ++j) accf8<SIGNED>(a, *(const uintx2*)(hb + (size_t)cc[j] * D), c120);
    }
    for (; p < e; ++p) accf8<SIGNED>(a, *(const uintx2*)(hb + (size_t)col[p] * D), c120);
    uintx4 r;
    r[0] = pk2(a[0] * sc, a[1] * sc);
    r[1] = pk2(a[2] * sc, a[3] * sc);
    r[2] = pk2(a[4] * sc, a[5] * sc);
    r[3] = pk2(a[6] * sc, a[7] * sc);
    *(uintx4*)(o + (size_t)node * D + li * 8) = r;
}

// ================= MFMA GEMM, LDS-resident fragment-ordered W =================

struct GArgs {
    const ushort *A1, *A2, *Wm, *Wv;
    const float *blm, *blv, *gm, *gv, *bbm, *bbv;
    void* out;
    uchar* out8;   // optional fp8 mirror of the LN output
};

template <int KH, int NOUT, bool DO_LN, bool DUAL, int ASTR, int AOFFM, int OSTR, int OOFFM, bool F8OUT>
__global__ __launch_bounds__(256, 2) void k_gemm(GArgs a) {
    constexpr int NT = NOUT / 16;
    constexpr int NK = KH / 16;
    constexpr int TW = DUAL ? 2 : 1;
    constexpr int WCH = NOUT * KH * 4 / 16;
    __shared__ uint4 wlds[TW * WCH];

    int tid = threadIdx.x;
    int lane = tid & 63, wid = tid >> 6;
    int tow = DUAL ? 0 : blockIdx.y;
    int aoff = tow * AOFFM;

    {
        const uint4* w0 = (const uint4*)(tow ? a.Wv : a.Wm);
        for (int i = tid; i < WCH; i += 256) wlds[i] = w0[i];
        if (DUAL) {
            const uint4* w1 = (const uint4*)a.Wv;
            for (int i = tid; i < WCH; i += 256) wlds[WCH + i] = w1[i];
        }
    }

    int r15 = lane & 15, kseg = lane >> 4;
    int m0 = blockIdx.x * 128 + wid * 32;
    size_t ar0 = (size_t)(m0 + r15);
    size_t ar1 = (size_t)(m0 + 16 + r15);

    short8 af[2][NK];
#pragma unroll
    for (int ks = 0; ks < NK; ++ks) {
        int kc = ks * 32 + kseg * 8;
        af[0][ks] = (kc < KH) ? *(const short8*)(a.A1 + ar0 * ASTR + aoff + kc)
                              : *(const short8*)(a.A2 + ar0 * ASTR + aoff + (kc - KH));
        af[1][ks] = (kc < KH) ? *(const short8*)(a.A1 + ar1 * ASTR + aoff + kc)
                              : *(const short8*)(a.A2 + ar1 * ASTR + aoff + (kc - KH));
    }
    __syncthreads();

    f32x4 acc[TW][2][NT];
#pragma unroll
    for (int tt = 0; tt < TW; ++tt)
#pragma unroll
        for (int t = 0; t < 2; ++t)
#pragma unroll
            for (int nt = 0; nt < NT; ++nt) acc[tt][t][nt] = (f32x4){0.f, 0.f, 0.f, 0.f};

#pragma unroll
    for (int ks = 0; ks < NK; ++ks) {
#pragma unroll
        for (int nt = 0; nt < NT; ++nt) {
#pragma unroll
            for (int tt = 0; tt < TW; ++tt) {
                short8 w = *(const short8*)&wlds[tt * WCH + (ks * NT + nt) * 64 + lane];
                acc[tt][0][nt] = __builtin_amdgcn_mfma_f32_16x16x32_bf16(af[0][ks], w, acc[tt][0][nt], 0, 0, 0);
                acc[tt][1][nt] = __builtin_amdgcn_mfma_f32_16x16x32_bf16(af[1][ks], w, acc[tt][1][nt], 0, 0, 0);
            }
        }
    }

#pragma unroll
    for (int tt = 0; tt < TW; ++tt) {
        int tsel = DUAL ? tt : tow;
        int ooff = tsel * OOFFM;
        const float* bl = tsel ? a.blv : a.blm;
#pragma unroll
        for (int nt = 0; nt < NT; ++nt) {
            float bb = bl[nt * 16 + r15];
#pragma unroll
            for (int t = 0; t < 2; ++t)
#pragma unroll
                for (int r = 0; r < 4; ++r) acc[tt][t][nt][r] += bb;
        }
        if (DO_LN) {
            const float* g = tsel ? a.gv : a.gm;
            const float* b = tsel ? a.bbv : a.bbm;
#pragma unroll
            for (int t = 0; t < 2; ++t) {
                float s[4] = {0, 0, 0, 0}, q[4] = {0, 0, 0, 0};
#pragma unroll
                for (int nt = 0; nt < NT; ++nt)
#pragma unroll
                    for (int r = 0; r < 4; ++r) { float v = acc[tt][t][nt][r]; s[r] += v; q[r] += v * v; }
#pragma unroll
                for (int off = 1; off < 16; off <<= 1)
#pragma unroll
                    for (int r = 0; r < 4; ++r) { s[r] += __shfl_xor(s[r], off); q[r] += __shfl_xor(q[r], off); }
                float mean[4], rstd[4];
#pragma unroll
                for (int r = 0; r < 4; ++r) {
                    mean[r] = s[r] * (1.0f / NOUT);
                    float var = q[r] * (1.0f / NOUT) - mean[r] * mean[r];
                    rstd[r] = rsqrtf(var + 1e-5f);
                }
                ushort* out = (ushort*)a.out;
#pragma unroll
                for (int nt = 0; nt < NT; ++nt) {
                    int n = nt * 16 + r15;
                    float gg = g[n], bb = b[n];
#pragma unroll
                    for (int r = 0; r < 4; ++r) {
                        int row = m0 + t * 16 + kseg * 4 + r;
                        if (row < NN) {
                            float y = fmaxf((acc[tt][t][nt][r] - mean[r]) * rstd[r] * gg + bb, 0.0f);
                            out[(size_t)row * OSTR + ooff + n] = f2b(y);
                            if (F8OUT) a.out8[(size_t)row * OSTR + ooff + n] = (uchar)enc8u(y);
                        }
                    }
                }
            }
        } else {
            float* out = (float*)a.out;
#pragma unroll
            for (int t = 0; t < 2; ++t)
#pragma unroll
                for (int nt = 0; nt < NT; ++nt) {
                    int n = nt * 16 + r15;
#pragma unroll
                    for (int r = 0; r < 4; ++r) {
                        int row = m0 + t * 16 + kseg * 4 + r;
                        if (row < NN) out[(size_t)row * OSTR + ooff + n] = acc[tt][t][nt][r];
                    }
                }
        }
    }
}

// ================= layer-2 split kernels (linearity) =================
// <false>: p2f8[node][tow*64+n] = fp8( h2p_tower @ Wl2^T )
// <true> : out[node][n] = h2p_tower @ Wr2^T + bl[n] + a2[node][tow*64+n]

struct G2Args {
    const ushort *A, *Wm, *Wv, *a2;
    const float *blm, *blv;
    void *outm, *outv;
};

template <bool FINAL>
__global__ __launch_bounds__(256, 2) void k_gemm2(G2Args a) {
    constexpr int NT = 4, NK = 4;
    constexpr int WCH = 1024;  // 16KB
    __shared__ uint4 wlds[WCH];

    int tid = threadIdx.x;
    int lane = tid & 63, wid = tid >> 6;
    int tow = blockIdx.y;
    {
        const uint4* w0 = (const uint4*)(tow ? a.Wv : a.Wm);
        for (int i = tid; i < WCH; i += 256) wlds[i] = w0[i];
    }
    int r15 = lane & 15, kseg = lane >> 4;
    int m0 = blockIdx.x * 128 + wid * 32;
    size_t ar0 = (size_t)(m0 + r15);
    size_t ar1 = (size_t)(m0 + 16 + r15);
    int aoff = tow * 128;

    short8 af[2][NK];
#pragma unroll
    for (int ks = 0; ks < NK; ++ks) {
        int kc = ks * 32 + kseg * 8;
        af[0][ks] = *(const short8*)(a.A + ar0 * 256 + aoff + kc);
        af[1][ks] = *(const short8*)(a.A + ar1 * 256 + aoff + kc);
    }
    __syncthreads();

    f32x4 acc[2][NT];
#pragma unroll
    for (int t = 0; t < 2; ++t)
#pragma unroll
        for (int nt = 0; nt < NT; ++nt) acc[t][nt] = (f32x4){0.f, 0.f, 0.f, 0.f};

#pragma unroll
    for (int ks = 0; ks < NK; ++ks) {
#pragma unroll
        for (int nt = 0; nt < NT; ++nt) {
            short8 w = *(const short8*)&wlds[(ks * NT + nt) * 64 + lane];
            acc[0][nt] = __builtin_amdgcn_mfma_f32_16x16x32_bf16(af[0][ks], w, acc[0][nt], 0, 0, 0);
            acc[1][nt] = __builtin_amdgcn_mfma_f32_16x16x32_bf16(af[1][ks], w, acc[1][nt], 0, 0, 0);
        }
    }

    if (FINAL) {
        const float* bl = tow ? a.blv : a.blm;
        float* out = (float*)(tow ? a.outv : a.outm);
#pragma unroll
        for (int t = 0; t < 2; ++t)
#pragma unroll
            for (int nt = 0; nt < NT; ++nt) {
                int n = nt * 16 + r15;
                float bb = bl[n];
#pragma unroll
                for (int r = 0; r < 4; ++r) {
                    int row = m0 + t * 16 + kseg * 4 + r;
                    if (row < NN) {
                        float av = blo((uint)a.a2[(size_t)row * 128 + tow * 64 + n]);
                        out[(size_t)row * 64 + n] = acc[t][nt][r] + bb + av;
                    }
                }
            }
    } else {
        uchar* out = (uchar*)a.outm;
#pragma unroll
        for (int t = 0; t < 2; ++t)
#pragma unroll
            for (int nt = 0; nt < NT; ++nt) {
                int n = nt * 16 + r15;
#pragma unroll
                for (int r = 0; r < 4; ++r) {
                    int row = m0 + t * 16 + kseg * 4 + r;
                    if (row < NN) out[(size_t)row * 128 + tow * 64 + n] = (uchar)enc8s(acc[t][nt][r]);
                }
            }
    }
}

// ================= launch =================

extern "C" void kernel_launch(void* const* d_in, const int* in_sizes, int n_in,
                              void* d_out, int out_size, void* d_ws, size_t ws_size,
                              hipStream_t stream) {
    const float* x = (const float*)d_in[0];
    const int* ei = (const int*)d_in[1];
    const int* esrc = ei;
    const int* edst = ei + NE;

    const float* mWl0 = (const float*)d_in[2];
    const float* mbl0 = (const float*)d_in[3];
    const float* mWr0 = (const float*)d_in[4];
    const float* mg0  = (const float*)d_in[5];
    const float* mb0  = (const float*)d_in[6];
    const float* mWl1 = (const float*)d_in[7];
    const float* mbl1 = (const float*)d_in[8];
    const float* mWr1 = (const float*)d_in[9];
    const float* mg1  = (const float*)d_in[10];
    const float* mb1  = (const float*)d_in[11];
    const float* mWl2 = (const float*)d_in[12];
    const float* mbl2 = (const float*)d_in[13];
    const float* mWr2 = (const float*)d_in[14];
    const float* vWl0 = (const float*)d_in[15];
    const float* vbl0 = (const float*)d_in[16];
    const float* vWr0 = (const float*)d_in[17];
    const float* vg0  = (const float*)d_in[18];
    const float* vb0  = (const float*)d_in[19];
    const float* vWl1 = (const float*)d_in[20];
    const float* vbl1 = (const float*)d_in[21];
    const float* vWr1 = (const float*)d_in[22];
    const float* vg1  = (const float*)d_in[23];
    const float* vb1  = (const float*)d_in[24];
    const float* vWl2 = (const float*)d_in[25];
    const float* vbl2 = (const float*)d_in[26];
    const float* vWr2 = (const float*)d_in[27];

    char* p = (char*)d_ws;
    auto alloc = [&](size_t bytes) {
        void* r = (void*)p;
        p += (bytes + 255) & ~(size_t)255;
        return r;
    };
    int* bhist     = (int*)alloc((size_t)FB * NBK * 4);
    int* pairRel   = (int*)alloc((size_t)FB * NBK * 4);
    int* bbase     = (int*)alloc((size_t)(NBK + 1) * 4);
    int* row_start = (int*)alloc((size_t)(NN + 1) * 4);
    float* inv_deg = (float*)alloc((size_t)NN * 4);
    int* col       = (int*)alloc((size_t)NE * 4);
    int2* pairs    = (int2*)alloc((size_t)NE * 8);     // reused as agg0 after F3
    ushort* agg0   = (ushort*)pairs;
    ushort* x_bf   = (ushort*)alloc((size_t)MPAD * 64 * 2);
    ushort* h1p    = (ushort*)alloc((size_t)MPAD * 256 * 2);
    ushort* h2p    = (ushort*)alloc((size_t)MPAD * 256 * 2);
    ushort* aggp   = (ushort*)alloc((size_t)MPAD * 256 * 2);
    uchar* h1f8    = (uchar*)h2p;                       // alias: dead until gemm1 writes h2p
    uchar* p2f8    = (uchar*)aggp;                      // alias: aggp dead after gemm1
    ushort* a2     = aggp + (size_t)MPAD * 128;         // second half of aggp region
    ushort* wc0    = (ushort*)alloc((size_t)128 * 128 * 2);
    ushort* wc1    = (ushort*)alloc((size_t)128 * 256 * 2);
    ushort* wc2    = (ushort*)alloc((size_t)64 * 128 * 2);
    ushort* wc3    = (ushort*)alloc((size_t)128 * 128 * 2);
    ushort* wc4    = (ushort*)alloc((size_t)128 * 256 * 2);
    ushort* wc5    = (ushort*)alloc((size_t)64 * 128 * 2);
    ushort* wc6    = (ushort*)alloc((size_t)64 * 128 * 2);
    ushort* wc7    = (ushort*)alloc((size_t)64 * 128 * 2);

    float* out_mu = (float*)d_out;
    float* out_lv = (float*)d_out + (size_t)NN * 64;

    // merged prep: f1 hist + weight cvt + x cvt
    PrepArgs pa;
    pa.x = x; pa.xb = x_bf; pa.edst = edst; pa.bhist = bhist;
    pa.w.srcA[0] = mWl0; pa.w.srcB[0] = mWr0; pa.w.dst[0] = wc0;
    pa.w.srcA[1] = mWl1; pa.w.srcB[1] = mWr1; pa.w.dst[1] = wc1;
    pa.w.srcA[2] = mWl2; pa.w.srcB[2] = nullptr; pa.w.dst[2] = wc2;
    pa.w.srcA[3] = nullptr; pa.w.srcB[3] = mWr2; pa.w.dst[3] = wc6;
    pa.w.srcA[4] = vWl0; pa.w.srcB[4] = vWr0; pa.w.dst[4] = wc3;
    pa.w.srcA[5] = vWl1; pa.w.srcB[5] = vWr1; pa.w.dst[5] = wc4;
    pa.w.srcA[6] = vWl2; pa.w.srcB[6] = nullptr; pa.w.dst[6] = wc5;
    pa.w.srcA[7] = nullptr; pa.w.srcB[7] = vWr2; pa.w.dst[7] = wc7;
    k_prep<<<FB + 512 + (NN * 32 + 255) / 256, 256, 0, stream>>>(pa);

    // bucketed CSR build
    k_fscan<<<1, 256, 0, stream>>>(bhist, pairRel, bbase);
    k_f2<<<FB, 256, 0, stream>>>(esrc, edst, pairRel, bbase, pairs);
    k_f3<<<NBK, 256, 0, stream>>>(pairs, bbase, row_start, inv_deg, col);

    const int gM = MPAD / 128;  // 391

    // layer 0: shared bf16 agg of x; DUAL GEMM -> packed h1p (bf16) + h1f8 (fp8)
    k_agg64<<<(NN * 16 + 255) / 256, 256, 0, stream>>>(x_bf, row_start, col, inv_deg, agg0);
    {
        GArgs ga = {agg0, x_bf, wc0, wc3, mbl0, vbl0, mg0, vg0, mb0, vb0, h1p, h1f8};
        k_gemm<64, 128, true, true, 64, 0, 256, 128, true><<<dim3(gM, 1), 256, 0, stream>>>(ga);
    }
    // layer 1: fp8 packed agg (halved gather bytes), packed GEMM -> h2p
    k_agg8<256, false><<<(NN * 32 + 255) / 256, 256, 0, stream>>>(h1f8, row_start, col, inv_deg, aggp);
    {
        GArgs ga = {aggp, h1p, wc1, wc4, mbl1, vbl1, mg1, vg1, mb1, vb1, h2p, nullptr};
        k_gemm<128, 128, true, false, 256, 128, 256, 128, false><<<dim3(gM, 2), 256, 0, stream>>>(ga);
    }
    // layer 2 via linearity: project (Wl) -> fp8 -> fp8 agg -> final (Wr + agg + bias)
    {
        G2Args g2 = {h2p, wc2, wc5, nullptr, nullptr, nullptr, p2f8, nullptr};
        k_gemm2<false><<<dim3(gM, 2), 256, 0, stream>>>(g2);
    }
    k_agg8<128, true><<<(NN * 16 + 255) / 256, 256, 0, stream>>>(p2f8, row_start, col, inv_deg, a2);
    {
        G2Args g2 = {h2p, wc6, wc7, a2, mbl2, vbl2, out_mu, out_lv};
        k_gemm2<true><<<dim3(gM, 2), 256, 0, stream>>>(g2);
    }
}

// Round 13
// 329.326 us; speedup vs baseline: 1.1923x; 1.0706x over previous
//
#include <hip/hip_runtime.h>

#define NN 50000
#define NE 800000
#define MPAD 50048    // 391 * 128
#define NBK 196       // buckets of 256 nodes
#define FB 98         // partition blocks
#define CH4 2048      // int4 per partition block (8192 edges)
#define EB4 200000    // NE/4
#define STAGE_CAP 6144

typedef __attribute__((ext_vector_type(8))) short short8;
typedef __attribute__((ext_vector_type(4))) float f32x4;
typedef uint __attribute__((ext_vector_type(4))) uintx4;
typedef uint __attribute__((ext_vector_type(2))) uintx2;

__device__ __forceinline__ ushort f2b(float f) {
    uint u = __builtin_bit_cast(uint, f);
    uint r = (u + 0x7fffu + ((u >> 16) & 1u)) >> 16;
    return (ushort)r;
}
__device__ __forceinline__ uint pk2(float a, float b) {
    return (uint)f2b(a) | ((uint)f2b(b) << 16);
}
__device__ __forceinline__ float blo(uint u) { return __builtin_bit_cast(float, u << 16); }
__device__ __forceinline__ float bhi(uint u) { return __builtin_bit_cast(float, u & 0xffff0000u); }

// ---- custom fp8 (e4m3-compatible, mul-trick codec) ----
__device__ __forceinline__ uint enc8u(float y) {   // y >= 0, y < 448
    uint b = __builtin_bit_cast(uint, y * 0x1p-120f) + (1u << 19);  // RN at bit 20
    return (b >> 20) & 0x7fu;
}
__device__ __forceinline__ uint enc8s(float y) {
    uint sb = __builtin_bit_cast(uint, y) & 0x80000000u;
    uint b = __builtin_bit_cast(uint, fabsf(y) * 0x1p-120f) + (1u << 19);
    return ((b >> 20) & 0x7fu) | (sb >> 24);
}

__device__ __forceinline__ void acc4(float* a, uintx2 u) {
    a[0] += blo(u[0]); a[1] += bhi(u[0]);
    a[2] += blo(u[1]); a[3] += bhi(u[1]);
}
template <bool SIGNED>
__device__ __forceinline__ void accf8(float* a, uintx2 u, float c120) {
#pragma unroll
    for (int w = 0; w < 2; ++w) {
        uint v = u[w];
#pragma unroll
        for (int j = 0; j < 4; ++j) {
            uint b = (v >> (8 * j)) & 0xffu;
            uint f = SIGNED ? (((b & 0x80u) << 24) | ((b & 0x7fu) << 20)) : (b << 20);
            a[w * 4 + j] += __builtin_bit_cast(float, f) * c120;
        }
    }
}

// ================= weight conversion args =================

struct W2Args {
    const float* srcA[8];
    const float* srcB[8];
    ushort* dst[8];
};

// ================= merged prep: f1 hist | wcvt | xcvt =================

struct PrepArgs {
    const float* x; ushort* xb;
    W2Args w;
    const int* edst; int* bhist;
};

__global__ __launch_bounds__(256) void k_prep(PrepArgs a) {
    __shared__ int h[NBK];
    int b = blockIdx.x;
    int t = threadIdx.x;
    if (b < FB) {
        for (int i = t; i < NBK; i += 256) h[i] = 0;
        __syncthreads();
        int i1 = min((b + 1) * CH4, EB4);
        for (int i = b * CH4 + t; i < i1; i += 256) {
            int4 d = ((const int4*)a.edst)[i];
            atomicAdd(&h[d.x >> 8], 1);
            atomicAdd(&h[d.y >> 8], 1);
            atomicAdd(&h[d.z >> 8], 1);
            atomicAdd(&h[d.w >> 8], 1);
        }
        __syncthreads();
        for (int i = t; i < NBK; i += 256) a.bhist[b * NBK + i] = h[i];
    } else if (b < FB + 512) {
        const int offT[8]   = {0, 16384, 49152, 57344, 65536, 81920, 114688, 122880};
        const int splitT[8] = {64, 128, 128, 0, 64, 128, 128, 0};
        const int logKKT[8] = {7, 8, 7, 7, 7, 8, 7, 7};
        const int ntT[8]    = {8, 8, 4, 4, 8, 8, 4, 4};
        int idx = (b - FB) * 256 + t;
        if (idx >= 131072) return;
        int L = 0;
#pragma unroll
        for (int i = 1; i < 8; ++i) if (idx >= offT[i]) L = i;
        int j = idx - offT[L];
        int lk = logKKT[L];
        int KK = 1 << lk;
        int n = j >> lk;
        int c = j & (KK - 1);
        int split = splitT[L];
        float v = (c < split) ? a.w.srcA[L][n * split + c]
                              : a.w.srcB[L][n * (KK - split) + (c - split)];
        int ks = c >> 5, kseg = (c >> 3) & 3, jj = c & 7;
        int nt = n >> 4, r15 = n & 15;
        int lane = (kseg << 4) | r15;
        int foff = ((ks * ntT[L] + nt) << 9) + (lane << 3) + jj;
        a.w.dst[L][foff] = f2b(v);
    } else {
        int i = (b - FB - 512) * 256 + t;
        if (i < NN * 32) {
            float2 v = *(const float2*)(a.x + (size_t)i * 2);
            *(uint*)(a.xb + (size_t)i * 2) = pk2(v.x, v.y);
        }
    }
}

// ================= bucketed CSR build =================

__global__ __launch_bounds__(256) void k_fscan(const int* __restrict__ bhist,
                                               int* __restrict__ pairRel,
                                               int* __restrict__ bbase) {
    __shared__ int tot[256];
    int b = threadIdx.x;
    int run = 0;
    if (b < NBK) {
        for (int blk = 0; blk < FB; ++blk) {
            int v = bhist[blk * NBK + b];
            pairRel[blk * NBK + b] = run;
            run += v;
        }
    }
    tot[b] = (b < NBK) ? run : 0;
    __syncthreads();
    for (int off = 1; off < 256; off <<= 1) {
        int t = (b >= off) ? tot[b - off] : 0;
        __syncthreads();
        tot[b] += t;
        __syncthreads();
    }
    if (b < NBK) bbase[b] = tot[b] - run;
    if (b == NBK - 1) bbase[NBK] = tot[b];
}

__global__ __launch_bounds__(256) void k_f2(const int* __restrict__ src, const int* __restrict__ dst,
                                            const int* __restrict__ pairRel,
                                            const int* __restrict__ bbase, int2* __restrict__ pairs) {
    __shared__ int cur[NBK];
    for (int i = threadIdx.x; i < NBK; i += 256)
        cur[i] = bbase[i] + pairRel[blockIdx.x * NBK + i];
    __syncthreads();
    int i1 = min((int)(blockIdx.x + 1) * CH4, EB4);
    for (int i = blockIdx.x * CH4 + threadIdx.x; i < i1; i += 256) {
        int4 s = ((const int4*)src)[i];
        int4 d = ((const int4*)dst)[i];
        int p0 = atomicAdd(&cur[d.x >> 8], 1);
        int p1 = atomicAdd(&cur[d.y >> 8], 1);
        int p2 = atomicAdd(&cur[d.z >> 8], 1);
        int p3 = atomicAdd(&cur[d.w >> 8], 1);
        pairs[p0] = (int2){s.x, d.x};
        pairs[p1] = (int2){s.y, d.y};
        pairs[p2] = (int2){s.z, d.z};
        pairs[p3] = (int2){s.w, d.w};
    }
}

__global__ __launch_bounds__(256) void k_f3(const int2* __restrict__ pairs,
                                            const int* __restrict__ bbase,
                                            int* __restrict__ row_start,
                                            float* __restrict__ inv_deg,
                                            int* __restrict__ col) {
    __shared__ int ndeg[256];
    __shared__ int noff[256];
    __shared__ int stage[STAGE_CAP];
    int b = blockIdx.x;
    int base = bbase[b], end = bbase[b + 1];
    int nbase = b << 8;
    int t = threadIdx.x;
    ndeg[t] = 0;
    __syncthreads();
    for (int p = base + t; p < end; p += 256) atomicAdd(&ndeg[pairs[p].y - nbase], 1);
    __syncthreads();
    int d = ndeg[t];
    noff[t] = d;
    __syncthreads();
    for (int off = 1; off < 256; off <<= 1) {
        int v = (t >= off) ? noff[t - off] : 0;
        __syncthreads();
        noff[t] += v;
        __syncthreads();
    }
    int excl = noff[t] - d;
    int node = nbase + t;
    if (node < NN) {
        row_start[node] = base + excl;
        inv_deg[node] = 1.0f / (float)(d > 1 ? d : 1);
    }
    if (b == 0 && t == 0) row_start[NN] = NE;
    __syncthreads();
    noff[t] = excl;
    __syncthreads();
    int cnt = end - base;
    for (int p = base + t; p < end; p += 256) {
        int2 pr = pairs[p];
        int pos = atomicAdd(&noff[pr.y - nbase], 1);
        if (pos < STAGE_CAP) stage[pos] = pr.x;
        else col[base + pos] = pr.x;
    }
    __syncthreads();
    int lim = cnt < STAGE_CAP ? cnt : STAGE_CAP;
    for (int i = t; i < lim; i += 256) col[base + i] = stage[i];
}

// ================= bf16 mean aggregation (layer 0, x table) =================

__global__ __launch_bounds__(256) void k_agg64(
    const ushort* __restrict__ h,
    const int* __restrict__ row_start, const int* __restrict__ col,
    const float* __restrict__ inv_deg, ushort* __restrict__ o) {
    int gid = blockIdx.x * 256 + threadIdx.x;
    int node = gid >> 4;
    int li = gid & 15;
    if (node >= NN) return;
    int s = row_start[node], e = row_start[node + 1];
    float sc = inv_deg[node];
    const ushort* hb = h + li * 4;
    float a[4] = {0, 0, 0, 0};
    int p = s;
    for (; p + 7 < e; p += 8) {
        int cc[8];
#pragma unroll
        for (int j = 0; j < 8; ++j) cc[j] = __builtin_nontemporal_load(col + p + j);
#pragma unroll
        for (int j = 0; j < 8; ++j) acc4(a, *(const uintx2*)(hb + (size_t)cc[j] * 64));
    }
    for (; p < e; ++p) acc4(a, *(const uintx2*)(hb + (size_t)col[p] * 64));
    uintx2 r;
    r[0] = pk2(a[0] * sc, a[1] * sc);
    r[1] = pk2(a[2] * sc, a[3] * sc);
    *(uintx2*)(o + (size_t)node * 64 + li * 4) = r;
}

// ================= fp8 mean aggregation (layers 1/2 tables) =================

template <int D, bool SIGNED>
__global__ __launch_bounds__(256) void k_agg8(
    const uchar* __restrict__ h,
    const int* __restrict__ row_start, const int* __restrict__ col,
    const float* __restrict__ inv_deg, ushort* __restrict__ o) {
    constexpr int LPN = D / 8;
    int gid = blockIdx.x * 256 + threadIdx.x;
    int node = gid / LPN;
    int li = gid & (LPN - 1);
    if (node >= NN) return;
    int s = row_start[node], e = row_start[node + 1];
    float sc = inv_deg[node];
    const uchar* hb = h + li * 8;
    const float c120 = 0x1p120f;
    float a[8] = {0, 0, 0, 0, 0, 0, 0, 0};
    int p = s;
    for (; p + 7 < e; p += 8) {
        int cc[8];
#pragma unroll
        for (int j = 0; j < 8; ++j) cc[j] = __builtin_nontemporal_load(col + p + j);
#pragma unroll
        for (int j = 0; j < 8; ++j) accf8<SIGNED>(a, *(const uintx2*)(hb + (size_t)cc[j] * D), c120);
    }
    for (; p < e; ++p) accf8<SIGNED>(a, *(const uintx2*)(hb + (size_t)col[p] * D), c120);
    uintx4 r;
    r[0] = pk2(a[0] * sc, a[1] * sc);
    r[1] = pk2(a[2] * sc, a[3] * sc);
    r[2] = pk2(a[4] * sc, a[5] * sc);
    r[3] = pk2(a[6] * sc, a[7] * sc);
    *(uintx4*)(o + (size_t)node * D + li * 8) = r;
}

// ================= MFMA GEMM: chunked double-buffered LDS W =================
// W chunks of 16KB (ks-blocks of the fragment stream) double-buffered -> 32KB LDS.
// A-fragments chunk-local, double-buffered in registers. Loop fully unrolled.
// RT = row-tiles of 16 per wave (BM = 64*RT).

struct GArgs {
    const ushort *A1, *A2, *Wm, *Wv;
    const float *blm, *blv, *gm, *gv, *bbm, *bbv;
    void* out;
    uchar* out8;   // optional fp8 mirror of the LN output
};

template <int KH, int NOUT, bool DO_LN, bool DUAL, int ASTR, int AOFFM, int OSTR, int OOFFM, bool F8OUT, int RT>
__global__ __launch_bounds__(256, 3) void k_gemm(GArgs a) {
    constexpr int NT = NOUT / 16;                       // 8
    constexpr int NK = KH / 16;                         // ks steps
    constexpr int TW = DUAL ? 2 : 1;
    constexpr int KSB = (TW * NT >= 16) ? 1 : (16 / (TW * NT));  // ks per 16KB chunk
    constexpr int NC = NK / KSB;                        // chunks
    constexpr int TCH = KSB * NT * 64;                  // uint4 per tower per chunk
    constexpr int CPT = TW * TCH;                       // uint4 per chunk (=1024 -> 16KB)
    __shared__ uint4 wlds[2][CPT];

    int tid = threadIdx.x;
    int lane = tid & 63, wid = tid >> 6;
    int tow = DUAL ? 0 : blockIdx.y;
    int aoff = tow * AOFFM;
    const uint4* w0g = (const uint4*)(tow ? a.Wv : a.Wm);
    const uint4* w1g = (const uint4*)a.Wv;

    int r15 = lane & 15, kseg = lane >> 4;
    int m0 = blockIdx.x * (64 * RT) + wid * (16 * RT);
    size_t ar[RT];
#pragma unroll
    for (int t = 0; t < RT; ++t) ar[t] = (size_t)(m0 + t * 16 + r15);

    short8 af[2][RT][KSB];

    auto stageW = [&](int c, int b) {
        const uint4* p0 = w0g + (size_t)c * TCH;
#pragma unroll
        for (int i = 0; i < TCH / 256; ++i) wlds[b][i * 256 + tid] = p0[i * 256 + tid];
        if (DUAL) {
            const uint4* p1 = w1g + (size_t)c * TCH;
#pragma unroll
            for (int i = 0; i < TCH / 256; ++i) wlds[b][TCH + i * 256 + tid] = p1[i * 256 + tid];
        }
    };
    auto loadA = [&](int c, int b) {
#pragma unroll
        for (int ko = 0; ko < KSB; ++ko) {
            int kc = (c * KSB + ko) * 32 + kseg * 8;
#pragma unroll
            for (int t = 0; t < RT; ++t)
                af[b][t][ko] = (kc < KH) ? *(const short8*)(a.A1 + ar[t] * ASTR + aoff + kc)
                                         : *(const short8*)(a.A2 + ar[t] * ASTR + aoff + (kc - KH));
        }
    };

    loadA(0, 0);
    stageW(0, 0);
    __syncthreads();

    f32x4 acc[TW][RT][NT];
#pragma unroll
    for (int tt = 0; tt < TW; ++tt)
#pragma unroll
        for (int t = 0; t < RT; ++t)
#pragma unroll
            for (int nt = 0; nt < NT; ++nt) acc[tt][t][nt] = (f32x4){0.f, 0.f, 0.f, 0.f};

#pragma unroll
    for (int c = 0; c < NC; ++c) {
        int b = c & 1;
        if (c + 1 < NC) { stageW(c + 1, b ^ 1); loadA(c + 1, b ^ 1); }
#pragma unroll
        for (int ko = 0; ko < KSB; ++ko) {
#pragma unroll
            for (int nt = 0; nt < NT; ++nt) {
#pragma unroll
                for (int tt = 0; tt < TW; ++tt) {
                    short8 w = *(const short8*)&wlds[b][tt * TCH + (ko * NT + nt) * 64 + lane];
#pragma unroll
                    for (int t = 0; t < RT; ++t)
                        acc[tt][t][nt] = __builtin_amdgcn_mfma_f32_16x16x32_bf16(af[b][t][ko], w, acc[tt][t][nt], 0, 0, 0);
                }
            }
        }
        __syncthreads();
    }

#pragma unroll
    for (int tt = 0; tt < TW; ++tt) {
        int tsel = DUAL ? tt : tow;
        int ooff = tsel * OOFFM;
        const float* bl = tsel ? a.blv : a.blm;
#pragma unroll
        for (int nt = 0; nt < NT; ++nt) {
            float bb = bl[nt * 16 + r15];
#pragma unroll
            for (int t = 0; t < RT; ++t)
#pragma unroll
                for (int r = 0; r < 4; ++r) acc[tt][t][nt][r] += bb;
        }
        if (DO_LN) {
            const float* g = tsel ? a.gv : a.gm;
            const float* b2 = tsel ? a.bbv : a.bbm;
#pragma unroll
            for (int t = 0; t < RT; ++t) {
                float s[4] = {0, 0, 0, 0}, q[4] = {0, 0, 0, 0};
#pragma unroll
                for (int nt = 0; nt < NT; ++nt)
#pragma unroll
                    for (int r = 0; r < 4; ++r) { float v = acc[tt][t][nt][r]; s[r] += v; q[r] += v * v; }
#pragma unroll
                for (int off = 1; off < 16; off <<= 1)
#pragma unroll
                    for (int r = 0; r < 4; ++r) { s[r] += __shfl_xor(s[r], off); q[r] += __shfl_xor(q[r], off); }
                float mean[4], rstd[4];
#pragma unroll
                for (int r = 0; r < 4; ++r) {
                    mean[r] = s[r] * (1.0f / NOUT);
                    float var = q[r] * (1.0f / NOUT) - mean[r] * mean[r];
                    rstd[r] = rsqrtf(var + 1e-5f);
                }
                ushort* out = (ushort*)a.out;
#pragma unroll
                for (int nt = 0; nt < NT; ++nt) {
                    int n = nt * 16 + r15;
                    float gg = g[n], bb = b2[n];
#pragma unroll
                    for (int r = 0; r < 4; ++r) {
                        int row = m0 + t * 16 + kseg * 4 + r;
                        if (row < NN) {
                            float y = fmaxf((acc[tt][t][nt][r] - mean[r]) * rstd[r] * gg + bb, 0.0f);
                            out[(size_t)row * OSTR + ooff + n] = f2b(y);
                            if (F8OUT) a.out8[(size_t)row * OSTR + ooff + n] = (uchar)enc8u(y);
                        }
                    }
                }
            }
        } else {
            float* out = (float*)a.out;
#pragma unroll
            for (int t = 0; t < RT; ++t)
#pragma unroll
                for (int nt = 0; nt < NT; ++nt) {
                    int n = nt * 16 + r15;
#pragma unroll
                    for (int r = 0; r < 4; ++r) {
                        int row = m0 + t * 16 + kseg * 4 + r;
                        if (row < NN) out[(size_t)row * OSTR + ooff + n] = acc[tt][t][nt][r];
                    }
                }
        }
    }
}

// ================= layer-2 split kernels (linearity) =================
// <false>: p2f8[node][tow*64+n] = fp8( h2p_tower @ Wl2^T )
// <true> : out[node][n] = h2p_tower @ Wr2^T + bl[n] + a2[node][tow*64+n]

struct G2Args {
    const ushort *A, *Wm, *Wv, *a2;
    const float *blm, *blv;
    void *outm, *outv;
};

template <bool FINAL>
__global__ __launch_bounds__(256, 2) void k_gemm2(G2Args a) {
    constexpr int NT = 4, NK = 4;
    constexpr int WCH = 1024;  // 16KB
    __shared__ uint4 wlds[WCH];

    int tid = threadIdx.x;
    int lane = tid & 63, wid = tid >> 6;
    int tow = blockIdx.y;
    {
        const uint4* w0 = (const uint4*)(tow ? a.Wv : a.Wm);
        for (int i = tid; i < WCH; i += 256) wlds[i] = w0[i];
    }
    int r15 = lane & 15, kseg = lane >> 4;
    int m0 = blockIdx.x * 128 + wid * 32;
    size_t ar0 = (size_t)(m0 + r15);
    size_t ar1 = (size_t)(m0 + 16 + r15);
    int aoff = tow * 128;

    short8 af[2][NK];
#pragma unroll
    for (int ks = 0; ks < NK; ++ks) {
        int kc = ks * 32 + kseg * 8;
        af[0][ks] = *(const short8*)(a.A + ar0 * 256 + aoff + kc);
        af[1][ks] = *(const short8*)(a.A + ar1 * 256 + aoff + kc);
    }
    __syncthreads();

    f32x4 acc[2][NT];
#pragma unroll
    for (int t = 0; t < 2; ++t)
#pragma unroll
        for (int nt = 0; nt < NT; ++nt) acc[t][nt] = (f32x4){0.f, 0.f, 0.f, 0.f};

#pragma unroll
    for (int ks = 0; ks < NK; ++ks) {
#pragma unroll
        for (int nt = 0; nt < NT; ++nt) {
            short8 w = *(const short8*)&wlds[(ks * NT + nt) * 64 + lane];
            acc[0][nt] = __builtin_amdgcn_mfma_f32_16x16x32_bf16(af[0][ks], w, acc[0][nt], 0, 0, 0);
            acc[1][nt] = __builtin_amdgcn_mfma_f32_16x16x32_bf16(af[1][ks], w, acc[1][nt], 0, 0, 0);
        }
    }

    if (FINAL) {
        const float* bl = tow ? a.blv : a.blm;
        float* out = (float*)(tow ? a.outv : a.outm);
#pragma unroll
        for (int t = 0; t < 2; ++t)
#pragma unroll
            for (int nt = 0; nt < NT; ++nt) {
                int n = nt * 16 + r15;
                float bb = bl[n];
#pragma unroll
                for (int r = 0; r < 4; ++r) {
                    int row = m0 + t * 16 + kseg * 4 + r;
                    if (row < NN) {
                        float av = blo((uint)a.a2[(size_t)row * 128 + tow * 64 + n]);
                        out[(size_t)row * 64 + n] = acc[t][nt][r] + bb + av;
                    }
                }
            }
    } else {
        uchar* out = (uchar*)a.outm;
#pragma unroll
        for (int t = 0; t < 2; ++t)
#pragma unroll
            for (int nt = 0; nt < NT; ++nt) {
                int n = nt * 16 + r15;
#pragma unroll
                for (int r = 0; r < 4; ++r) {
                    int row = m0 + t * 16 + kseg * 4 + r;
                    if (row < NN) out[(size_t)row * 128 + tow * 64 + n] = (uchar)enc8s(acc[t][nt][r]);
                }
            }
    }
}

// ================= launch =================

extern "C" void kernel_launch(void* const* d_in, const int* in_sizes, int n_in,
                              void* d_out, int out_size, void* d_ws, size_t ws_size,
                              hipStream_t stream) {
    const float* x = (const float*)d_in[0];
    const int* ei = (const int*)d_in[1];
    const int* esrc = ei;
    const int* edst = ei + NE;

    const float* mWl0 = (const float*)d_in[2];
    const float* mbl0 = (const float*)d_in[3];
    const float* mWr0 = (const float*)d_in[4];
    const float* mg0  = (const float*)d_in[5];
    const float* mb0  = (const float*)d_in[6];
    const float* mWl1 = (const float*)d_in[7];
    const float* mbl1 = (const float*)d_in[8];
    const float* mWr1 = (const float*)d_in[9];
    const float* mg1  = (const float*)d_in[10];
    const float* mb1  = (const float*)d_in[11];
    const float* mWl2 = (const float*)d_in[12];
    const float* mbl2 = (const float*)d_in[13];
    const float* mWr2 = (const float*)d_in[14];
    const float* vWl0 = (const float*)d_in[15];
    const float* vbl0 = (const float*)d_in[16];
    const float* vWr0 = (const float*)d_in[17];
    const float* vg0  = (const float*)d_in[18];
    const float* vb0  = (const float*)d_in[19];
    const float* vWl1 = (const float*)d_in[20];
    const float* vbl1 = (const float*)d_in[21];
    const float* vWr1 = (const float*)d_in[22];
    const float* vg1  = (const float*)d_in[23];
    const float* vb1  = (const float*)d_in[24];
    const float* vWl2 = (const float*)d_in[25];
    const float* vbl2 = (const float*)d_in[26];
    const float* vWr2 = (const float*)d_in[27];

    char* p = (char*)d_ws;
    auto alloc = [&](size_t bytes) {
        void* r = (void*)p;
        p += (bytes + 255) & ~(size_t)255;
        return r;
    };
    int* bhist     = (int*)alloc((size_t)FB * NBK * 4);
    int* pairRel   = (int*)alloc((size_t)FB * NBK * 4);
    int* bbase     = (int*)alloc((size_t)(NBK + 1) * 4);
    int* row_start = (int*)alloc((size_t)(NN + 1) * 4);
    float* inv_deg = (float*)alloc((size_t)NN * 4);
    int* col       = (int*)alloc((size_t)NE * 4);
    int2* pairs    = (int2*)alloc((size_t)NE * 8);     // reused as agg0 after F3
    ushort* agg0   = (ushort*)pairs;
    ushort* x_bf   = (ushort*)alloc((size_t)MPAD * 64 * 2);
    ushort* h1p    = (ushort*)alloc((size_t)MPAD * 256 * 2);
    ushort* h2p    = (ushort*)alloc((size_t)MPAD * 256 * 2);
    ushort* aggp   = (ushort*)alloc((size_t)MPAD * 256 * 2);
    uchar* h1f8    = (uchar*)h2p;                       // alias: dead until gemm1 writes h2p
    uchar* p2f8    = (uchar*)aggp;                      // alias: aggp dead after gemm1
    ushort* a2     = aggp + (size_t)MPAD * 128;         // second half of aggp region
    ushort* wc0    = (ushort*)alloc((size_t)128 * 128 * 2);
    ushort* wc1    = (ushort*)alloc((size_t)128 * 256 * 2);
    ushort* wc2    = (ushort*)alloc((size_t)64 * 128 * 2);
    ushort* wc3    = (ushort*)alloc((size_t)128 * 128 * 2);
    ushort* wc4    = (ushort*)alloc((size_t)128 * 256 * 2);
    ushort* wc5    = (ushort*)alloc((size_t)64 * 128 * 2);
    ushort* wc6    = (ushort*)alloc((size_t)64 * 128 * 2);
    ushort* wc7    = (ushort*)alloc((size_t)64 * 128 * 2);

    float* out_mu = (float*)d_out;
    float* out_lv = (float*)d_out + (size_t)NN * 64;

    // merged prep: f1 hist + weight cvt + x cvt
    PrepArgs pa;
    pa.x = x; pa.xb = x_bf; pa.edst = edst; pa.bhist = bhist;
    pa.w.srcA[0] = mWl0; pa.w.srcB[0] = mWr0; pa.w.dst[0] = wc0;
    pa.w.srcA[1] = mWl1; pa.w.srcB[1] = mWr1; pa.w.dst[1] = wc1;
    pa.w.srcA[2] = mWl2; pa.w.srcB[2] = nullptr; pa.w.dst[2] = wc2;
    pa.w.srcA[3] = nullptr; pa.w.srcB[3] = mWr2; pa.w.dst[3] = wc6;
    pa.w.srcA[4] = vWl0; pa.w.srcB[4] = vWr0; pa.w.dst[4] = wc3;
    pa.w.srcA[5] = vWl1; pa.w.srcB[5] = vWr1; pa.w.dst[5] = wc4;
    pa.w.srcA[6] = vWl2; pa.w.srcB[6] = nullptr; pa.w.dst[6] = wc5;
    pa.w.srcA[7] = nullptr; pa.w.srcB[7] = vWr2; pa.w.dst[7] = wc7;
    k_prep<<<FB + 512 + (NN * 32 + 255) / 256, 256, 0, stream>>>(pa);

    // bucketed CSR build
    k_fscan<<<1, 256, 0, stream>>>(bhist, pairRel, bbase);
    k_f2<<<FB, 256, 0, stream>>>(esrc, edst, pairRel, bbase, pairs);
    k_f3<<<NBK, 256, 0, stream>>>(pairs, bbase, row_start, inv_deg, col);

    // layer 0: shared bf16 agg of x; DUAL GEMM (RT=1, BM=64) -> h1p (bf16) + h1f8 (fp8)
    k_agg64<<<(NN * 16 + 255) / 256, 256, 0, stream>>>(x_bf, row_start, col, inv_deg, agg0);
    {
        GArgs ga = {agg0, x_bf, wc0, wc3, mbl0, vbl0, mg0, vg0, mb0, vb0, h1p, h1f8};
        k_gemm<64, 128, true, true, 64, 0, 256, 128, true, 1><<<dim3(MPAD / 64, 1), 256, 0, stream>>>(ga);
    }
    // layer 1: fp8 packed agg, chunked GEMM (RT=2, BM=128) -> h2p
    k_agg8<256, false><<<(NN * 32 + 255) / 256, 256, 0, stream>>>(h1f8, row_start, col, inv_deg, aggp);
    {
        GArgs ga = {aggp, h1p, wc1, wc4, mbl1, vbl1, mg1, vg1, mb1, vb1, h2p, nullptr};
        k_gemm<128, 128, true, false, 256, 128, 256, 128, false, 2><<<dim3(MPAD / 128, 2), 256, 0, stream>>>(ga);
    }
    // layer 2 via linearity: project (Wl) -> fp8 -> fp8 agg -> final (Wr + agg + bias)
    {
        G2Args g2 = {h2p, wc2, wc5, nullptr, nullptr, nullptr, p2f8, nullptr};
        k_gemm2<false><<<dim3(MPAD / 128, 2), 256, 0, stream>>>(g2);
    }
    k_agg8<128, true><<<(NN * 16 + 255) / 256, 256, 0, stream>>>(p2f8, row_start, col, inv_deg, a2);
    {
        G2Args g2 = {h2p, wc6, wc7, a2, mbl2, vbl2, out_mu, out_lv};
        k_gemm2<true><<<dim3(MPAD / 128, 2), 256, 0, stream>>>(g2);
    }
}